// Round 13
// baseline (18892.972 us; speedup 1.0000x reference)
//
#include <hip/hip_runtime.h>

typedef __attribute__((ext_vector_type(8))) short short8;
typedef __attribute__((ext_vector_type(8))) _Float16 f16x8;
typedef __attribute__((ext_vector_type(4))) float f32x4;

#define GENF 100
#define TCOND 50
#define BATCH 128
#define HID 1024
#define INP 171
#define INPAD 192
#define OUTN 171
#define OUTPAD 176
#define SPLITS 4
#define TILES 64
#define NBLK 256

static __device__ __forceinline__ unsigned short f2h(float f) {
  _Float16 h = (_Float16)f;  // round-to-nearest-even
  return __builtin_bit_cast(unsigned short, h);
}
static __device__ __forceinline__ float h2f(unsigned short s) {
  return (float)__builtin_bit_cast(_Float16, s);
}
static __device__ __forceinline__ f16x8 ld8(const unsigned short* p) {
  short8 v = *reinterpret_cast<const short8*>(p);
  return __builtin_bit_cast(f16x8, v);
}
static __device__ __forceinline__ float sigm(float x) { return 1.f / (1.f + __expf(-x)); }

// Phase gate (R9-proven): arrivals are RELEASE-fenced by finishers; waiters
// relaxed-poll the monotonic counter, then one ACQUIRE refreshes this CU's
// caches (1 block/CU). Cheap: only 64 (or 88) arrivals per phase.
static __device__ __forceinline__ void wait_phase(unsigned* ctr, unsigned tgt) {
  __syncthreads();
  if (threadIdx.x == 0) {
    while (__hip_atomic_load(ctr, __ATOMIC_RELAXED, __HIP_MEMORY_SCOPE_AGENT) < tgt)
      __builtin_amdgcn_s_sleep(4);
    (void)__hip_atomic_load(ctr, __ATOMIC_ACQUIRE, __HIP_MEMORY_SCOPE_AGENT);
  }
  __syncthreads();
}

struct Params {
  const unsigned short* xch; const unsigned short* xcl;
  unsigned short* fxh; unsigned short* fxl;
  const unsigned short* wH[3];
  const float* bias[3];
  float* c[3];
  unsigned short* hh[3][2]; unsigned short* hl[3][2];
  const unsigned short* wd; const float* bd;
  float* out;
  float* partials;
  unsigned* counters;
  unsigned* phase_ctr;
};

// One LSTM layer phase (R12 body): fp16x2 split-K GEMM (A=hi+lo fp16 pair, W
// single fp16), 3 rotating LDS bufs, depth-2 prefetch, counted vmcnt(20);
// counter-elected finisher does the cell epilogue then RELEASE-arrives.
static __device__ __forceinline__ void layer_phase(
    char* smem, int blk,
    const unsigned short* __restrict__ xh_, const unsigned short* __restrict__ xl_,
    int ldx, int xc,
    const unsigned short* __restrict__ hh_, const unsigned short* __restrict__ hl_,
    const unsigned short* __restrict__ wH,
    int ldw, int NK,
    const float* __restrict__ bias,
    float* __restrict__ c,
    unsigned short* __restrict__ ohh, unsigned short* __restrict__ ohl,
    float* __restrict__ partials, unsigned* __restrict__ counters,
    unsigned* __restrict__ phase_ctr)
{
  const int t = threadIdx.x;
  const int lane = t & 63, wv = t >> 6;
  const int nt = blk & (TILES - 1), sp = blk >> 6;
  const int n0 = nt * 64 + wv * 16;  // wave's 16-col strip (perm space)
  const int nit = NK / SPLITS;       // even
  const int beg = sp * nit;
  const int ns = nit >> 1;           // super-iters (2 chunks each)

  const int r_row = lane & 15, kg = lane >> 4;
  const int rslot = kg ^ (r_row & 3);  // swizzled 16B slot for ds_read
  const int srow = t >> 2;             // staging row (+ j*64)
  const size_t bcol = (size_t)(n0 + r_row) * ldw + kg * 8;

  auto stage1 = [&](char* dst, int ck) {
    const unsigned short *sh, *sl;
    int ld, k0;
    if (ck < xc) { sh = xh_; sl = xl_; ld = ldx; k0 = ck * 32; }
    else { sh = hh_; sl = hl_; ld = HID; k0 = (ck - xc) * 32; }
#pragma unroll
    for (int j = 0; j < 2; ++j) {
      int rowp = j * 64 + srow;
      int slot = (t & 3) ^ (rowp & 3);  // inverse-swizzled global source
      const unsigned short* gh = sh + (size_t)rowp * ld + k0 + slot * 8;
      const unsigned short* gl = sl + (size_t)rowp * ld + k0 + slot * 8;
      char* dh = dst + j * 4096 + wv * 1024;
      char* dl = dst + 8192 + j * 4096 + wv * 1024;
      __builtin_amdgcn_global_load_lds((const __attribute__((address_space(1))) void*)gh,
                                       (__attribute__((address_space(3))) void*)dh, 16, 0, 0);
      __builtin_amdgcn_global_load_lds((const __attribute__((address_space(1))) void*)gl,
                                       (__attribute__((address_space(3))) void*)dl, 16, 0, 0);
    }
  };

  f32x4 zz = {0.f, 0.f, 0.f, 0.f};
  f32x4 acc[8] = {zz, zz, zz, zz, zz, zz, zz, zz};

  char* bA = smem;
  char* bB = smem + 32768;
  char* bC = smem + 65536;

  stage1(bA, beg);
  stage1(bA + 16384, beg + 1);
  f16x8 b0h0 = ld8(wH + bcol + (size_t)(beg + 0) * 32);
  f16x8 b0h1 = ld8(wH + bcol + (size_t)(beg + 1) * 32);
  __builtin_amdgcn_sched_barrier(0);
  stage1(bB, beg + 2);
  stage1(bB + 16384, beg + 3);
  f16x8 b1h0 = ld8(wH + bcol + (size_t)(beg + 2) * 32);
  f16x8 b1h1 = ld8(wH + bcol + (size_t)(beg + 3) * 32);
  __builtin_amdgcn_sched_barrier(0);

  for (int i = 0; i < ns; ++i) {
    int ck = beg + 2 * i + 4;
    if (ck >= beg + nit) ck = beg;  // clamped junk tail (uniform counts, unused)
    stage1(bC, ck);
    stage1(bC + 16384, ck + 1);
    f16x8 b2h0 = ld8(wH + bcol + (size_t)ck * 32);
    f16x8 b2h1 = ld8(wH + bcol + (size_t)(ck + 1) * 32);
    __builtin_amdgcn_sched_barrier(0);

    asm volatile("s_waitcnt vmcnt(20)" ::: "memory");
    __builtin_amdgcn_s_barrier();
    __builtin_amdgcn_sched_barrier(0);

#pragma unroll
    for (int ch = 0; ch < 2; ++ch) {
      f16x8 ah[8], al[8];
#pragma unroll
      for (int rg = 0; rg < 8; ++rg) {
        int ro = ch * 16384 + (rg * 16 + r_row) * 64 + rslot * 16;
        ah[rg] = *reinterpret_cast<const f16x8*>(bA + ro);
        al[rg] = *reinterpret_cast<const f16x8*>(bA + ro + 8192);
      }
      f16x8 BH = ch ? b0h1 : b0h0;
#pragma unroll
      for (int rg = 0; rg < 8; ++rg)
        acc[rg] = __builtin_amdgcn_mfma_f32_16x16x32_f16(ah[rg], BH, acc[rg], 0, 0, 0);
#pragma unroll
      for (int rg = 0; rg < 8; ++rg)
        acc[rg] = __builtin_amdgcn_mfma_f32_16x16x32_f16(al[rg], BH, acc[rg], 0, 0, 0);
    }
    __builtin_amdgcn_sched_barrier(0);
    __builtin_amdgcn_s_barrier();  // all waves done reading bA before restage

    char* tmp = bA; bA = bB; bB = bC; bC = tmp;
    b0h0 = b1h0; b0h1 = b1h1;
    b1h0 = b2h0; b1h1 = b2h1;
  }

  // ---- store split partials ----
  {
    float* pb = partials + (size_t)sp * (BATCH * 4096);
    const int cn = n0 + r_row;
    const int mb = kg * 4;
#pragma unroll
    for (int rg = 0; rg < 8; ++rg)
#pragma unroll
      for (int r = 0; r < 4; ++r)
        pb[(size_t)(rg * 16 + mb + r) * 4096 + cn] = acc[rg][r];
  }

  __syncthreads();  // drain stores + junk staging
  __shared__ unsigned oldv;
  if (t == 0)
    oldv = __hip_atomic_fetch_add(&counters[nt], 1u, __ATOMIC_ACQ_REL, __HIP_MEMORY_SCOPE_AGENT);
  __syncthreads();
  if (oldv != SPLITS - 1) return;

  // ---- finisher: reduce splits + LSTM cell for this tile's 16 hid cols ----
  (void)__hip_atomic_load(&counters[nt], __ATOMIC_ACQUIRE, __HIP_MEMORY_SCOPE_AGENT);
  const int fc = t & 15, fm = t >> 4;
  const int nh = nt * 16 + fc;
  const f32x4 bv = *reinterpret_cast<const f32x4*>(&bias[nh * 4]);
#pragma unroll
  for (int p = 0; p < 8; ++p) {
    int m = fm + p * 16;
    size_t gi0 = (size_t)m * 4096 + nh * 4;
    f32x4 s = *reinterpret_cast<const f32x4*>(&partials[gi0]);
#pragma unroll
    for (int q = 1; q < SPLITS; ++q)
      s += *reinterpret_cast<const f32x4*>(&partials[gi0 + (size_t)q * BATCH * 4096]);
    float gi = sigm(s[0] + bv[0]);
    float gf = sigm(s[1] + bv[1]);
    float gg = tanhf(s[2] + bv[2]);
    float go = sigm(s[3] + bv[3]);
    size_t sidx = (size_t)m * HID + nh;
    float cn2 = gf * c[sidx] + gi * gg;
    c[sidx] = cn2;
    float h = go * tanhf(cn2);
    unsigned short h16 = f2h(h);
    ohh[sidx] = h16;
    ohl[sidx] = f2h(h - h2f(h16));
  }
  __syncthreads();  // drain h/c writes before release
  if (t == 0) {
    __hip_atomic_store(&counters[nt], 0u, __ATOMIC_RELAXED, __HIP_MEMORY_SCOPE_AGENT);
    __hip_atomic_fetch_add(phase_ctr, 1u, __ATOMIC_RELEASE, __HIP_MEMORY_SCOPE_AGENT);
  }
}

// Decoder phase: blocks 0..87; fp16x2; RELEASE-arrives when done.
static __device__ __forceinline__ void dec_phase(
    char* smem, int blk,
    const unsigned short* __restrict__ hhi, const unsigned short* __restrict__ hlo,
    const unsigned short* __restrict__ wd,
    const float* __restrict__ bd, float* __restrict__ outp,
    unsigned short* __restrict__ fxhi, unsigned short* __restrict__ fxlo,
    unsigned* __restrict__ phase_ctr)
{
  const int wave = threadIdx.x >> 6, lane = threadIdx.x & 63;
  const int n0 = (blk % 11) * 16;
  const int m0 = (blk / 11) * 16;
  const int row = lane & 15, kg = lane >> 4;
  f32x4 acc = {0.f, 0.f, 0.f, 0.f};
  const unsigned short* pah = hhi + (size_t)(m0 + row) * HID + kg * 8 + wave * 256;
  const unsigned short* pal = hlo + (size_t)(m0 + row) * HID + kg * 8 + wave * 256;
  const unsigned short* pbh = wd + (size_t)(n0 + row) * HID + kg * 8 + wave * 256;
#pragma unroll
  for (int kk = 0; kk < 8; ++kk) {
    int off2 = kk * 32;
    f16x8 a1 = ld8(pah + off2), a2 = ld8(pal + off2);
    f16x8 b1 = ld8(pbh + off2);
    acc = __builtin_amdgcn_mfma_f32_16x16x32_f16(a1, b1, acc, 0, 0, 0);
    acc = __builtin_amdgcn_mfma_f32_16x16x32_f16(a2, b1, acc, 0, 0, 0);
  }
  f32x4 (*red)[64] = (f32x4(*)[64])smem;
  if (wave) red[wave][lane] = acc;
  __syncthreads();
  if (wave == 0) {
    acc += red[1][lane];
    acc += red[2][lane];
    acc += red[3][lane];
    const int col = lane & 15, rg = lane >> 4;
#pragma unroll
    for (int r = 0; r < 4; ++r) {
      int m = m0 + rg * 4 + r;
      int n = n0 + col;
      if (n < OUTN) {
        float v = acc[r] + bd[n];
        if (outp) outp[(size_t)m * (GENF * OUTN) + n] = v;
        unsigned short vh = f2h(v);
        fxhi[(size_t)m * INPAD + n] = vh;
        fxlo[(size_t)m * INPAD + n] = f2h(v - h2f(vh));
      }
    }
  }
  __syncthreads();  // drain fx/out writes before release
  if (threadIdx.x == 0)
    __hip_atomic_fetch_add(phase_ctr, 1u, __ATOMIC_RELEASE, __HIP_MEMORY_SCOPE_AGENT);
}

// Persistent kernel: all 150 steps; strict phase barriers (R9 sync), cached
// fp16 weights (44MB total -> L3-resident, no re-fetch from HBM per step).
__global__ __launch_bounds__(256) void lstm_persist_k(Params p) {
  __shared__ __align__(16) char smem[98304];
  const int blk = blockIdx.x;
  unsigned tgt = 0;
  for (int s = 0; s < TCOND + GENF; ++s) {
    const int pp = s & 1, np = pp ^ 1;
    for (int L = 0; L < 3; ++L) {
      const unsigned short *xh, *xl;
      int ldx, xc, ldw, NK;
      if (L == 0) {
        if (s < TCOND) {
          xh = p.xch + (size_t)s * BATCH * INPAD;
          xl = p.xcl + (size_t)s * BATCH * INPAD;
        } else {
          xh = p.fxh;
          xl = p.fxl;
        }
        ldx = INPAD; xc = INPAD / 32; ldw = 1280; NK = 40;
      } else {
        xh = p.hh[L - 1][np]; xl = p.hl[L - 1][np];
        ldx = HID; xc = HID / 32; ldw = 2 * HID; NK = 64;
      }
      layer_phase(smem, blk, xh, xl, ldx, xc, p.hh[L][pp], p.hl[L][pp],
                  p.wH[L], ldw, NK, p.bias[L], p.c[L],
                  p.hh[L][np], p.hl[L][np], p.partials, p.counters, p.phase_ctr);
      tgt += TILES;
      wait_phase(p.phase_ctr, tgt);
    }
    if (s >= TCOND - 1) {
      if (blk < 88) {
        float* outp = (s >= TCOND) ? p.out + (size_t)(s - TCOND) * OUTN : (float*)0;
        dec_phase(smem, blk, p.hh[2][np], p.hl[2][np], p.wd, p.bd,
                  outp, p.fxh, p.fxl, p.phase_ctr);
      }
      tgt += 88;
      wait_phase(p.phase_ctr, tgt);
    }
  }
}

// ---- prep kernels ----
// LSTM weight: src [4096 gate-major][C] f32 -> dst rows permuted (nh*4+g), cols
// at [co, co+Cpad) of a [4096][dstride] fp16 buffer.
__global__ void cvt_w_k(const float* __restrict__ src, unsigned short* __restrict__ w16,
                        int C, int Cpad, int co, int dstride)
{
  int idx = blockIdx.x * 256 + threadIdx.x;
  if (idx >= 4096 * Cpad) return;
  int r = idx / Cpad, cc = idx - r * Cpad;
  float v = (cc < C) ? src[(size_t)r * C + cc] : 0.f;
  int rp = (r & 1023) * 4 + (r >> 10);
  w16[(size_t)rp * dstride + co + cc] = f2h(v);
}

__global__ void cvt_wd_k(const float* __restrict__ src, unsigned short* __restrict__ w16,
                         int R, int C, int Rp, int Cp)
{
  int idx = blockIdx.x * 256 + threadIdx.x;
  if (idx >= Rp * Cp) return;
  int r = idx / Cp, c2 = idx - r * Cp;
  float v = (r < R && c2 < C) ? src[(size_t)r * C + c2] : 0.f;
  w16[idx] = f2h(v);
}

__global__ void bias_perm_k(const float* __restrict__ a, const float* __restrict__ b,
                            float* __restrict__ dst)
{
  int i = blockIdx.x * 256 + threadIdx.x;
  if (i < 4096) dst[(i & 1023) * 4 + (i >> 10)] = a[i] + b[i];
}

__global__ void biaspad_k(const float* __restrict__ a, float* __restrict__ dst, int n, int np)
{
  int i = blockIdx.x * 256 + threadIdx.x;
  if (i < np) dst[i] = (i < n) ? a[i] : 0.f;
}

// initial_seq [B][T][IN] fp32 -> xcond hi/lo [T][B][INPAD] fp16 (zero-padded cols)
__global__ void xcond_k(const float* __restrict__ seq, unsigned short* __restrict__ xhi,
                        unsigned short* __restrict__ xlo)
{
  int idx = blockIdx.x * 256 + threadIdx.x;
  const int total = TCOND * BATCH * INPAD;
  if (idx >= total) return;
  int t = idx / (BATCH * INPAD);
  int rem = idx - t * (BATCH * INPAD);
  int b = rem / INPAD;
  int k = rem - b * INPAD;
  float v = (k < INP) ? seq[((size_t)b * TCOND + t) * INP + k] : 0.f;
  unsigned short h = f2h(v);
  xhi[idx] = h;
  xlo[idx] = f2h(v - h2f(h));
}

extern "C" void kernel_launch(void* const* d_in, const int* in_sizes, int n_in,
                              void* d_out, int out_size, void* d_ws, size_t ws_size,
                              hipStream_t stream)
{
  (void)in_sizes; (void)n_in; (void)out_size;
  const float* seq   = (const float*)d_in[0];
  const float* w_ih1 = (const float*)d_in[2];
  const float* w_hh1 = (const float*)d_in[3];
  const float* b_ih1 = (const float*)d_in[4];
  const float* b_hh1 = (const float*)d_in[5];
  const float* w_ih2 = (const float*)d_in[6];
  const float* w_hh2 = (const float*)d_in[7];
  const float* b_ih2 = (const float*)d_in[8];
  const float* b_hh2 = (const float*)d_in[9];
  const float* w_ih3 = (const float*)d_in[10];
  const float* w_hh3 = (const float*)d_in[11];
  const float* b_ih3 = (const float*)d_in[12];
  const float* b_hh3 = (const float*)d_in[13];
  const float* w_dec = (const float*)d_in[14];
  const float* b_dec = (const float*)d_in[15];
  float* out = (float*)d_out;

  char* ws = (char*)d_ws;
  size_t off = 0;
  auto alloc = [&](size_t bytes) -> char* {
    off = (off + 255) & ~(size_t)255;
    char* p = ws + off;
    off += bytes;
    return p;
  };
  auto us = [&](size_t n) { return (unsigned short*)alloc(n * 2); };
  auto fl = [&](size_t n) { return (float*)alloc(n * 4); };

  const int K1P = 1280;        // padded: 192 + 1024 = 1216 -> 1280 (NK=40)
  const int K2 = 2 * HID;      // 2048 (NK=64)
  unsigned short *W1 = us((size_t)4096 * K1P);
  unsigned short *W2 = us((size_t)4096 * K2);
  unsigned short *W3 = us((size_t)4096 * K2);
  unsigned short *wd = us((size_t)OUTPAD * HID);
  float *b1 = fl(4096), *b2 = fl(4096), *b3 = fl(4096), *bd = fl(OUTPAD);
  unsigned short *xch = us((size_t)TCOND * BATCH * INPAD), *xcl = us((size_t)TCOND * BATCH * INPAD);
  float* partials = fl((size_t)SPLITS * BATCH * 4096);

  size_t state_beg = (off + 255) & ~(size_t)255;
  float *c0 = fl((size_t)BATCH * HID), *c1 = fl((size_t)BATCH * HID), *c2 = fl((size_t)BATCH * HID);
  unsigned short* Hh[3][2];
  unsigned short* Hl[3][2];
  for (int L = 0; L < 3; ++L)
    for (int p = 0; p < 2; ++p) {
      Hh[L][p] = us((size_t)BATCH * HID);
      Hl[L][p] = us((size_t)BATCH * HID);
    }
  unsigned short *fxh = us((size_t)BATCH * INPAD), *fxl = us((size_t)BATCH * INPAD);
  unsigned* counters = (unsigned*)alloc(TILES * 4);
  unsigned* phase_ctr = (unsigned*)alloc(4);
  size_t state_end = off;

  if (off > ws_size) return;  // scratch too small; fail visibly

  hipMemsetAsync(ws + state_beg, 0, state_end - state_beg, stream);
  // zero W1 pad columns (1216..1280) — memset whole W1 before cvt fills real cols
  hipMemsetAsync(W1, 0, (size_t)4096 * K1P * 2, stream);

  // ---- weight / input prep ----
  auto cw = [&](const float* s, unsigned short* w, int C, int Cpad, int co, int ds2) {
    int n = 4096 * Cpad;
    cvt_w_k<<<(n + 255) / 256, 256, 0, stream>>>(s, w, C, Cpad, co, ds2);
  };
  cw(w_ih1, W1, INP, INPAD, 0, K1P);
  cw(w_hh1, W1, HID, HID, INPAD, K1P);
  cw(w_ih2, W2, HID, HID, 0, K2);
  cw(w_hh2, W2, HID, HID, HID, K2);
  cw(w_ih3, W3, HID, HID, 0, K2);
  cw(w_hh3, W3, HID, HID, HID, K2);
  {
    int n = OUTPAD * HID;
    cvt_wd_k<<<(n + 255) / 256, 256, 0, stream>>>(w_dec, wd, OUTN, HID, OUTPAD, HID);
  }
  bias_perm_k<<<16, 256, 0, stream>>>(b_ih1, b_hh1, b1);
  bias_perm_k<<<16, 256, 0, stream>>>(b_ih2, b_hh2, b2);
  bias_perm_k<<<16, 256, 0, stream>>>(b_ih3, b_hh3, b3);
  biaspad_k<<<1, 256, 0, stream>>>(b_dec, bd, OUTN, OUTPAD);
  {
    int n = TCOND * BATCH * INPAD;
    xcond_k<<<(n + 255) / 256, 256, 0, stream>>>(seq, xch, xcl);
  }

  // ---- single persistent kernel: all 150 steps ----
  Params P;
  P.xch = xch; P.xcl = xcl; P.fxh = fxh; P.fxl = fxl;
  P.wH[0] = W1; P.wH[1] = W2; P.wH[2] = W3;
  P.bias[0] = b1; P.bias[1] = b2; P.bias[2] = b3;
  P.c[0] = c0; P.c[1] = c1; P.c[2] = c2;
  for (int L = 0; L < 3; ++L)
    for (int p2 = 0; p2 < 2; ++p2) {
      P.hh[L][p2] = Hh[L][p2];
      P.hl[L][p2] = Hl[L][p2];
    }
  P.wd = wd; P.bd = bd;
  P.out = out;
  P.partials = partials;
  P.counters = counters;
  P.phase_ctr = phase_ctr;
  lstm_persist_k<<<NBLK, 256, 0, stream>>>(P);
}

// Round 14
// 17994.075 us; speedup vs baseline: 1.0500x; 1.0500x over previous
//
#include <hip/hip_runtime.h>

typedef __attribute__((ext_vector_type(8))) short short8;
typedef __attribute__((ext_vector_type(8))) _Float16 f16x8;
typedef __attribute__((ext_vector_type(4))) float f32x4;

#define GENF 100
#define TCOND 50
#define BATCH 128
#define HID 1024
#define INP 171
#define INPAD 192
#define OUTN 171
#define OUTPAD 176

static __device__ __forceinline__ unsigned short f2h(float f) {
  _Float16 h = (_Float16)f;  // round-to-nearest-even
  return __builtin_bit_cast(unsigned short, h);
}
static __device__ __forceinline__ float h2f(unsigned short s) {
  return (float)__builtin_bit_cast(_Float16, s);
}
static __device__ __forceinline__ f16x8 ld8(const unsigned short* p) {
  short8 v = *reinterpret_cast<const short8*>(p);
  return __builtin_bit_cast(f16x8, v);
}
static __device__ __forceinline__ float sigm(float x) { return 1.f / (1.f + __expf(-x)); }

// Fused LSTM layer, ATOMIC-FREE: block = 16 perm-cols (4 nh) x FULL K; 4 waves
// M-split (wave w = batch rows 32w..32w+31) -> each wave's acc is the complete
// gate sum. No split-K partials, no counters, no elections, no agent atomics
// -> L2 is never invalidated mid-phase; W strip (64KB/block) and the shared
// A-broadcast stay L2-resident across the phase.
// K-loop: R10-proven 3 rotating LDS bufs (2 chunks = 32KB each), depth-2
// prefetch, counted s_waitcnt vmcnt(20) (2 supers x 10 VMEM/wave in flight).
// W layout: [4096 perm rows (nh*4+g)][ldw] fp16, k-space = x-cols || h-cols.
// Grid: 256 blocks x 256 thr. NK must be even, >= 6.
__global__ __launch_bounds__(256) void lstm_gemm_k(
    const unsigned short* __restrict__ xh_, const unsigned short* __restrict__ xl_,
    int ldx, int xc,
    const unsigned short* __restrict__ hh_, const unsigned short* __restrict__ hl_,
    const unsigned short* __restrict__ wH,
    int ldw, int NK,
    const float* __restrict__ bias,
    float* __restrict__ c,
    unsigned short* __restrict__ ohh, unsigned short* __restrict__ ohl)
{
  __shared__ __align__(16) char smem[98304];  // 3 bufs x 2 chunks x (hi 8K + lo 8K)
  const int t = threadIdx.x;
  const int lane = t & 63, wv = t >> 6;
  const int blk = blockIdx.x;
  const int ns = NK >> 1;  // super-iters (2 chunks each)

  const int r_row = lane & 15, kg = lane >> 4;
  const int rslot = kg ^ (r_row & 3);  // swizzled 16B slot for ds_read
  const int srow = t >> 2;             // staging row (+ j*64)
  const size_t bcol = (size_t)(blk * 16 + r_row) * ldw + kg * 8;
  const int arow = wv * 32;            // wave's 32-row batch slice

  // stage one 32-k chunk (A hi/lo, 128 rows) into 16KB at dst
  auto stage1 = [&](char* dst, int ck) {
    const unsigned short *sh, *sl;
    int ld, k0;
    if (ck < xc) { sh = xh_; sl = xl_; ld = ldx; k0 = ck * 32; }
    else { sh = hh_; sl = hl_; ld = HID; k0 = (ck - xc) * 32; }
#pragma unroll
    for (int j = 0; j < 2; ++j) {
      int rowp = j * 64 + srow;
      int slot = (t & 3) ^ (rowp & 3);  // inverse-swizzled global source
      const unsigned short* gh = sh + (size_t)rowp * ld + k0 + slot * 8;
      const unsigned short* gl = sl + (size_t)rowp * ld + k0 + slot * 8;
      char* dh = dst + j * 4096 + wv * 1024;
      char* dl = dst + 8192 + j * 4096 + wv * 1024;
      __builtin_amdgcn_global_load_lds((const __attribute__((address_space(1))) void*)gh,
                                       (__attribute__((address_space(3))) void*)dh, 16, 0, 0);
      __builtin_amdgcn_global_load_lds((const __attribute__((address_space(1))) void*)gl,
                                       (__attribute__((address_space(3))) void*)dl, 16, 0, 0);
    }
  };

  f32x4 zz = {0.f, 0.f, 0.f, 0.f};
  f32x4 acc0 = zz, acc1 = zz;  // rows arow..+15 / arow+16..+31, cols blk*16+..

  char* bA = smem;
  char* bB = smem + 32768;
  char* bC = smem + 65536;

  // prologue: supers 0 and 1 in flight (10 VMEM ops/wave each, issue-grouped)
  stage1(bA, 0);
  stage1(bA + 16384, 1);
  f16x8 b0h0 = ld8(wH + bcol + (size_t)0 * 32);
  f16x8 b0h1 = ld8(wH + bcol + (size_t)1 * 32);
  __builtin_amdgcn_sched_barrier(0);
  stage1(bB, 2);
  stage1(bB + 16384, 3);
  f16x8 b1h0 = ld8(wH + bcol + (size_t)2 * 32);
  f16x8 b1h1 = ld8(wH + bcol + (size_t)3 * 32);
  __builtin_amdgcn_sched_barrier(0);

  for (int i = 0; i < ns; ++i) {
    // issue super i+2 (clamped to 0 on tail iters: uniform counts, junk unused)
    int ck = 2 * i + 4;
    if (ck >= NK) ck = 0;
    stage1(bC, ck);
    stage1(bC + 16384, ck + 1);
    f16x8 b2h0 = ld8(wH + bcol + (size_t)ck * 32);
    f16x8 b2h1 = ld8(wH + bcol + (size_t)(ck + 1) * 32);
    __builtin_amdgcn_sched_barrier(0);

    // wait: super i retired (20 = supers i+1, i+2 stay in flight)
    asm volatile("s_waitcnt vmcnt(20)" ::: "memory");
    __builtin_amdgcn_s_barrier();
    __builtin_amdgcn_sched_barrier(0);

#pragma unroll
    for (int ch = 0; ch < 2; ++ch) {
      int ro = ch * 16384 + (arow + r_row) * 64 + rslot * 16;
      f16x8 ah0 = *reinterpret_cast<const f16x8*>(bA + ro);
      f16x8 al0 = *reinterpret_cast<const f16x8*>(bA + ro + 8192);
      f16x8 ah1 = *reinterpret_cast<const f16x8*>(bA + ro + 1024);
      f16x8 al1 = *reinterpret_cast<const f16x8*>(bA + ro + 1024 + 8192);
      f16x8 BH = ch ? b0h1 : b0h0;
      acc0 = __builtin_amdgcn_mfma_f32_16x16x32_f16(ah0, BH, acc0, 0, 0, 0);
      acc0 = __builtin_amdgcn_mfma_f32_16x16x32_f16(al0, BH, acc0, 0, 0, 0);
      acc1 = __builtin_amdgcn_mfma_f32_16x16x32_f16(ah1, BH, acc1, 0, 0, 0);
      acc1 = __builtin_amdgcn_mfma_f32_16x16x32_f16(al1, BH, acc1, 0, 0, 0);
    }
    __builtin_amdgcn_sched_barrier(0);
    __builtin_amdgcn_s_barrier();  // all waves done reading bA before restage

    char* tmp = bA; bA = bB; bB = bC; bC = tmp;
    b0h0 = b1h0; b0h1 = b1h1;
    b1h0 = b2h0; b1h1 = b2h1;
  }

  // ---- in-block epilogue: transpose gates via LDS, fused LSTM cell ----
  asm volatile("s_waitcnt vmcnt(0)" ::: "memory");  // drain junk staging DMAs
  __builtin_amdgcn_s_barrier();

  // gbuf: per-wave [32 rows][16 perm-cols] f32 at smem + wv*2KB
  float* gb = reinterpret_cast<float*>(smem) + wv * 512;
#pragma unroll
  for (int r = 0; r < 4; ++r) {
    gb[(kg * 4 + r) * 16 + r_row] = acc0[r];
    gb[(16 + kg * 4 + r) * 16 + r_row] = acc1[r];
  }
  __syncthreads();

#pragma unroll
  for (int e = 0; e < 2; ++e) {
    int o = e * 64 + lane;        // 128 outputs per wave: (row_local, nh_local)
    int rl = o >> 2, c0 = o & 3;
    f32x4 g4 = *reinterpret_cast<const f32x4*>(gb + rl * 16 + c0 * 4);  // i,f,g,o
    int nh_g = blk * 4 + c0;
    f32x4 bv = *reinterpret_cast<const f32x4*>(&bias[nh_g * 4]);
    float gi = sigm(g4[0] + bv[0]);
    float gf = sigm(g4[1] + bv[1]);
    float gg = tanhf(g4[2] + bv[2]);
    float go = sigm(g4[3] + bv[3]);
    size_t sidx = (size_t)(arow + rl) * HID + nh_g;
    float cn2 = gf * c[sidx] + gi * gg;
    c[sidx] = cn2;
    float h = go * tanhf(cn2);
    unsigned short h16 = f2h(h);
    ohh[sidx] = h16;
    ohl[sidx] = f2h(h - h2f(h16));
  }
}

// Decoder: out = h2 @ w_dec^T + b_dec. 4 waves split K, LDS reduce. fp16x2.
__global__ __launch_bounds__(256) void dec_k(
    const unsigned short* __restrict__ hhi, const unsigned short* __restrict__ hlo,
    const unsigned short* __restrict__ wdh,
    const float* __restrict__ bd,
    float* __restrict__ outp,
    unsigned short* __restrict__ fxhi, unsigned short* __restrict__ fxlo)
{
  const int wave = threadIdx.x >> 6, lane = threadIdx.x & 63;
  const int n0 = ((int)blockIdx.x % 11) * 16;
  const int m0 = ((int)blockIdx.x / 11) * 16;
  const int row = lane & 15, kg = lane >> 4;
  f32x4 acc = {0.f, 0.f, 0.f, 0.f};
  const unsigned short* pah = hhi + (size_t)(m0 + row) * HID + kg * 8 + wave * 256;
  const unsigned short* pal = hlo + (size_t)(m0 + row) * HID + kg * 8 + wave * 256;
  const unsigned short* pbh = wdh + (size_t)(n0 + row) * HID + kg * 8 + wave * 256;
#pragma unroll
  for (int kk = 0; kk < 8; ++kk) {
    int off = kk * 32;
    f16x8 a1 = ld8(pah + off), a2 = ld8(pal + off);
    f16x8 b1 = ld8(pbh + off);
    acc = __builtin_amdgcn_mfma_f32_16x16x32_f16(a1, b1, acc, 0, 0, 0);
    acc = __builtin_amdgcn_mfma_f32_16x16x32_f16(a2, b1, acc, 0, 0, 0);
  }
  __shared__ f32x4 red[4][64];
  if (wave) red[wave][lane] = acc;
  __syncthreads();
  if (wave == 0) {
    acc += red[1][lane];
    acc += red[2][lane];
    acc += red[3][lane];
    const int col = lane & 15, rg = lane >> 4;
#pragma unroll
    for (int r = 0; r < 4; ++r) {
      int m = m0 + rg * 4 + r;
      int n = n0 + col;
      if (n < OUTN) {
        float v = acc[r] + bd[n];
        if (outp) outp[(size_t)m * (GENF * OUTN) + n] = v;
        unsigned short vh = f2h(v);
        fxhi[(size_t)m * INPAD + n] = vh;
        fxlo[(size_t)m * INPAD + n] = f2h(v - h2f(vh));
      }
    }
  }
}

// ---- prep kernels ----
// LSTM weight: src [4096 gate-major][C] f32 -> dst rows permuted (nh*4+g), cols
// at [co, co+Cpad) of a [4096][dstride] fp16 buffer.
__global__ void cvt_w_k(const float* __restrict__ src, unsigned short* __restrict__ w16,
                        int C, int Cpad, int co, int dstride)
{
  int idx = blockIdx.x * 256 + threadIdx.x;
  if (idx >= 4096 * Cpad) return;
  int r = idx / Cpad, cc = idx - r * Cpad;
  float v = (cc < C) ? src[(size_t)r * C + cc] : 0.f;
  int rp = (r & 1023) * 4 + (r >> 10);
  w16[(size_t)rp * dstride + co + cc] = f2h(v);
}

__global__ void cvt_wd_k(const float* __restrict__ src, unsigned short* __restrict__ w16,
                         int R, int C, int Rp, int Cp)
{
  int idx = blockIdx.x * 256 + threadIdx.x;
  if (idx >= Rp * Cp) return;
  int r = idx / Cp, c2 = idx - r * Cp;
  float v = (r < R && c2 < C) ? src[(size_t)r * C + c2] : 0.f;
  w16[idx] = f2h(v);
}

__global__ void bias_perm_k(const float* __restrict__ a, const float* __restrict__ b,
                            float* __restrict__ dst)
{
  int i = blockIdx.x * 256 + threadIdx.x;
  if (i < 4096) dst[(i & 1023) * 4 + (i >> 10)] = a[i] + b[i];
}

__global__ void biaspad_k(const float* __restrict__ a, float* __restrict__ dst, int n, int np)
{
  int i = blockIdx.x * 256 + threadIdx.x;
  if (i < np) dst[i] = (i < n) ? a[i] : 0.f;
}

// initial_seq [B][T][IN] fp32 -> xcond hi/lo [T][B][INPAD] fp16 (zero-padded cols)
__global__ void xcond_k(const float* __restrict__ seq, unsigned short* __restrict__ xhi,
                        unsigned short* __restrict__ xlo)
{
  int idx = blockIdx.x * 256 + threadIdx.x;
  const int total = TCOND * BATCH * INPAD;
  if (idx >= total) return;
  int t = idx / (BATCH * INPAD);
  int rem = idx - t * (BATCH * INPAD);
  int b = rem / INPAD;
  int k = rem - b * INPAD;
  float v = (k < INP) ? seq[((size_t)b * TCOND + t) * INP + k] : 0.f;
  unsigned short h = f2h(v);
  xhi[idx] = h;
  xlo[idx] = f2h(v - h2f(h));
}

extern "C" void kernel_launch(void* const* d_in, const int* in_sizes, int n_in,
                              void* d_out, int out_size, void* d_ws, size_t ws_size,
                              hipStream_t stream)
{
  (void)in_sizes; (void)n_in; (void)out_size;
  const float* seq   = (const float*)d_in[0];
  const float* w_ih1 = (const float*)d_in[2];
  const float* w_hh1 = (const float*)d_in[3];
  const float* b_ih1 = (const float*)d_in[4];
  const float* b_hh1 = (const float*)d_in[5];
  const float* w_ih2 = (const float*)d_in[6];
  const float* w_hh2 = (const float*)d_in[7];
  const float* b_ih2 = (const float*)d_in[8];
  const float* b_hh2 = (const float*)d_in[9];
  const float* w_ih3 = (const float*)d_in[10];
  const float* w_hh3 = (const float*)d_in[11];
  const float* b_ih3 = (const float*)d_in[12];
  const float* b_hh3 = (const float*)d_in[13];
  const float* w_dec = (const float*)d_in[14];
  const float* b_dec = (const float*)d_in[15];
  float* out = (float*)d_out;

  char* ws = (char*)d_ws;
  size_t off = 0;
  auto alloc = [&](size_t bytes) -> char* {
    off = (off + 255) & ~(size_t)255;
    char* p = ws + off;
    off += bytes;
    return p;
  };
  auto us = [&](size_t n) { return (unsigned short*)alloc(n * 2); };
  auto fl = [&](size_t n) { return (float*)alloc(n * 4); };

  const int K1P = 1280;        // padded: 192 + 1024 = 1216 -> 1280 (NK=40 even)
  const int K2 = 2 * HID;      // 2048 (NK=64)
  unsigned short *W1 = us((size_t)4096 * K1P);
  unsigned short *W2 = us((size_t)4096 * K2);
  unsigned short *W3 = us((size_t)4096 * K2);
  unsigned short *wd = us((size_t)OUTPAD * HID);
  float *b1 = fl(4096), *b2 = fl(4096), *b3 = fl(4096), *bd = fl(OUTPAD);
  unsigned short *xch = us((size_t)TCOND * BATCH * INPAD), *xcl = us((size_t)TCOND * BATCH * INPAD);

  size_t state_beg = (off + 255) & ~(size_t)255;
  float *c0 = fl((size_t)BATCH * HID), *c1 = fl((size_t)BATCH * HID), *c2 = fl((size_t)BATCH * HID);
  unsigned short* Hh[3][2];
  unsigned short* Hl[3][2];
  for (int L = 0; L < 3; ++L)
    for (int p = 0; p < 2; ++p) {
      Hh[L][p] = us((size_t)BATCH * HID);
      if (L == 0) alloc(4096);  // zero guard: L1 pad chunks read past last h row
      Hl[L][p] = us((size_t)BATCH * HID);
      if (L == 0) alloc(4096);
    }
  unsigned short *fxh = us((size_t)BATCH * INPAD), *fxl = us((size_t)BATCH * INPAD);
  size_t state_end = off;

  if (off > ws_size) return;  // scratch too small; fail visibly

  hipMemsetAsync(ws + state_beg, 0, state_end - state_beg, stream);
  // zero W1 pad columns (1216..1280) — memset whole W1 before cvt fills real cols
  hipMemsetAsync(W1, 0, (size_t)4096 * K1P * 2, stream);

  // ---- weight / input prep ----
  auto cw = [&](const float* s, unsigned short* w, int C, int Cpad, int co, int ds2) {
    int n = 4096 * Cpad;
    cvt_w_k<<<(n + 255) / 256, 256, 0, stream>>>(s, w, C, Cpad, co, ds2);
  };
  cw(w_ih1, W1, INP, INPAD, 0, K1P);
  cw(w_hh1, W1, HID, HID, INPAD, K1P);
  cw(w_ih2, W2, HID, HID, 0, K2);
  cw(w_hh2, W2, HID, HID, HID, K2);
  cw(w_ih3, W3, HID, HID, 0, K2);
  cw(w_hh3, W3, HID, HID, HID, K2);
  {
    int n = OUTPAD * HID;
    cvt_wd_k<<<(n + 255) / 256, 256, 0, stream>>>(w_dec, wd, OUTN, HID, OUTPAD, HID);
  }
  bias_perm_k<<<16, 256, 0, stream>>>(b_ih1, b_hh1, b1);
  bias_perm_k<<<16, 256, 0, stream>>>(b_ih2, b_hh2, b2);
  bias_perm_k<<<16, 256, 0, stream>>>(b_ih3, b_hh3, b3);
  biaspad_k<<<1, 256, 0, stream>>>(b_dec, bd, OUTN, OUTPAD);
  {
    int n = TCOND * BATCH * INPAD;
    xcond_k<<<(n + 255) / 256, 256, 0, stream>>>(seq, xch, xcl);
  }

  // ---- recurrent loop: 150 steps, atomic-free kernels, boundary sync only ----
  for (int s = 0; s < TCOND + GENF; ++s) {
    const unsigned short *xh, *xl;
    if (s < TCOND) {
      xh = xch + (size_t)s * BATCH * INPAD;
      xl = xcl + (size_t)s * BATCH * INPAD;
    } else {
      xh = fxh;
      xl = fxl;
    }
    int pp = s & 1, np = pp ^ 1;
    lstm_gemm_k<<<256, 256, 0, stream>>>(xh, xl, INPAD, INPAD / 32,
        Hh[0][pp], Hl[0][pp], W1, K1P, K1P / 32, b1, c0, Hh[0][np], Hl[0][np]);
    lstm_gemm_k<<<256, 256, 0, stream>>>(Hh[0][np], Hl[0][np], HID, HID / 32,
        Hh[1][pp], Hl[1][pp], W2, K2, K2 / 32, b2, c1, Hh[1][np], Hl[1][np]);
    lstm_gemm_k<<<256, 256, 0, stream>>>(Hh[1][np], Hl[1][np], HID, HID / 32,
        Hh[2][pp], Hl[2][pp], W3, K2, K2 / 32, b3, c2, Hh[2][np], Hl[2][np]);
    if (s == TCOND - 1) {
      dec_k<<<88, 256, 0, stream>>>(Hh[2][np], Hl[2][np], wd, bd,
                                    (float*)nullptr, fxh, fxl);
    } else if (s >= TCOND) {
      dec_k<<<88, 256, 0, stream>>>(Hh[2][np], Hl[2][np], wd, bd,
                                    out + (size_t)(s - TCOND) * OUTN, fxh, fxl);
    }
  }
}

// Round 15
// 17587.567 us; speedup vs baseline: 1.0742x; 1.0231x over previous
//
#include <hip/hip_runtime.h>

typedef __attribute__((ext_vector_type(8))) short short8;
typedef __attribute__((ext_vector_type(8))) _Float16 f16x8;
typedef __attribute__((ext_vector_type(4))) float f32x4;

#define GENF 100
#define TCOND 50
#define BATCH 128
#define HID 1024
#define INP 171
#define INPAD 192
#define OUTN 171
#define OUTPAD 176
#define SPLITS 8
#define TILES 64

static __device__ __forceinline__ unsigned short f2h(float f) {
  _Float16 h = (_Float16)f;  // round-to-nearest-even
  return __builtin_bit_cast(unsigned short, h);
}
static __device__ __forceinline__ float h2f(unsigned short s) {
  return (float)__builtin_bit_cast(_Float16, s);
}
static __device__ __forceinline__ f16x8 ld8(const unsigned short* p) {
  short8 v = *reinterpret_cast<const short8*>(p);
  return __builtin_bit_cast(f16x8, v);
}
static __device__ __forceinline__ float sigm(float x) { return 1.f / (1.f + __expf(-x)); }

// Fused LSTM layer: fp16x2 split-K GEMM + counter-elected finisher cell epilogue.
// R15: SPLITS=8 -> 512 blocks = 2 blocks/CU (8 waves/CU) for cross-block latency
// hiding; LDS 64KB (2 bufs, depth-1 prefetch, counted vmcnt(10) = one 10-op super
// in flight). A tile's 8 splits share an XCD (blk&63=nt) -> L2-local partials.
// W layout: [4096 perm rows (nh*4+g)][ldw] fp16, k-space = x-cols || h-cols.
// nit = NK/SPLITS must be even. nkr = real (non-pad) chunk count; pad staging
// reads are clamped to chunk 0 (W pad cols are zero, so contribution is 0).
__global__ __launch_bounds__(256) void lstm_gemm_k(
    const unsigned short* __restrict__ xh_, const unsigned short* __restrict__ xl_,
    int ldx, int xc,
    const unsigned short* __restrict__ hh_, const unsigned short* __restrict__ hl_,
    const unsigned short* __restrict__ wH,
    int ldw, int NK, int nkr,
    const float* __restrict__ bias,
    float* __restrict__ c,
    unsigned short* __restrict__ ohh, unsigned short* __restrict__ ohl,
    float* __restrict__ partials, unsigned* __restrict__ counters)
{
  __shared__ __align__(16) char smem[65536];  // 2 bufs x 2 chunks x (hi 8K + lo 8K)
  const int t = threadIdx.x;
  const int lane = t & 63, wv = t >> 6;
  const int nt = blockIdx.x & (TILES - 1), sp = blockIdx.x >> 6;
  const int n0 = nt * 64 + wv * 16;  // wave's 16-col strip (perm space)
  const int nit = NK / SPLITS;       // even
  const int beg = sp * nit;
  const int ns = nit >> 1;           // super-iters (2 chunks each)

  const int r_row = lane & 15, kg = lane >> 4;
  const int rslot = kg ^ (r_row & 3);  // swizzled 16B slot for ds_read
  const int srow = t >> 2;             // staging row (+ j*64)
  const size_t bcol = (size_t)(n0 + r_row) * ldw + kg * 8;

  // stage one 32-col k-chunk (A hi/lo, 128 rows) into 16KB at dst.
  // pad chunks (ck >= nkr) clamp to chunk 0: valid reads, W pad cols are zero.
  auto stage1 = [&](char* dst, int ck) {
    if (ck >= nkr) ck = 0;
    const unsigned short *sh, *sl;
    int ld, k0;
    if (ck < xc) { sh = xh_; sl = xl_; ld = ldx; k0 = ck * 32; }
    else { sh = hh_; sl = hl_; ld = HID; k0 = (ck - xc) * 32; }
#pragma unroll
    for (int j = 0; j < 2; ++j) {
      int rowp = j * 64 + srow;
      int slot = (t & 3) ^ (rowp & 3);  // inverse-swizzled global source
      const unsigned short* gh = sh + (size_t)rowp * ld + k0 + slot * 8;
      const unsigned short* gl = sl + (size_t)rowp * ld + k0 + slot * 8;
      char* dh = dst + j * 4096 + wv * 1024;
      char* dl = dst + 8192 + j * 4096 + wv * 1024;
      __builtin_amdgcn_global_load_lds((const __attribute__((address_space(1))) void*)gh,
                                       (__attribute__((address_space(3))) void*)dh, 16, 0, 0);
      __builtin_amdgcn_global_load_lds((const __attribute__((address_space(1))) void*)gl,
                                       (__attribute__((address_space(3))) void*)dl, 16, 0, 0);
    }
  };

  f32x4 zz = {0.f, 0.f, 0.f, 0.f};
  f32x4 acc[8] = {zz, zz, zz, zz, zz, zz, zz, zz};

  char* bA = smem;
  char* bB = smem + 32768;

  // prologue: super 0 in flight (10 VMEM ops/wave, issue-grouped)
  stage1(bA, beg);
  stage1(bA + 16384, beg + 1);
  f16x8 b0h0 = ld8(wH + bcol + (size_t)(beg + 0) * 32);
  f16x8 b0h1 = ld8(wH + bcol + (size_t)(beg + 1) * 32);
  __builtin_amdgcn_sched_barrier(0);

  for (int i = 0; i < ns; ++i) {
    // issue super i+1 (clamped junk on last iter: uniform counts, unused)
    int ck = beg + 2 * i + 2;
    if (ck >= beg + nit) ck = beg;
    stage1(bB, ck);
    stage1(bB + 16384, ck + 1);
    f16x8 b1h0 = ld8(wH + bcol + (size_t)ck * 32);
    f16x8 b1h1 = ld8(wH + bcol + (size_t)(ck + 1) * 32);
    __builtin_amdgcn_sched_barrier(0);

    // wait: super i retired (10 = super i+1 stays in flight)
    asm volatile("s_waitcnt vmcnt(10)" ::: "memory");
    __builtin_amdgcn_s_barrier();
    __builtin_amdgcn_sched_barrier(0);

#pragma unroll
    for (int ch = 0; ch < 2; ++ch) {
      f16x8 ah[8], al[8];
#pragma unroll
      for (int rg = 0; rg < 8; ++rg) {
        int ro = ch * 16384 + (rg * 16 + r_row) * 64 + rslot * 16;
        ah[rg] = *reinterpret_cast<const f16x8*>(bA + ro);
        al[rg] = *reinterpret_cast<const f16x8*>(bA + ro + 8192);
      }
      f16x8 BH = ch ? b0h1 : b0h0;
#pragma unroll
      for (int rg = 0; rg < 8; ++rg)
        acc[rg] = __builtin_amdgcn_mfma_f32_16x16x32_f16(ah[rg], BH, acc[rg], 0, 0, 0);
#pragma unroll
      for (int rg = 0; rg < 8; ++rg)
        acc[rg] = __builtin_amdgcn_mfma_f32_16x16x32_f16(al[rg], BH, acc[rg], 0, 0, 0);
    }
    __builtin_amdgcn_sched_barrier(0);
    __builtin_amdgcn_s_barrier();  // all waves done reading bA before restage

    char* tmp = bA; bA = bB; bB = tmp;
    b0h0 = b1h0; b0h1 = b1h1;
  }

  // ---- store split partials (plain f32 stores) ----
  {
    float* pb = partials + (size_t)sp * (BATCH * 4096);
    const int cn = n0 + r_row;
    const int mb = kg * 4;
#pragma unroll
    for (int rg = 0; rg < 8; ++rg)
#pragma unroll
      for (int r = 0; r < 4; ++r)
        pb[(size_t)(rg * 16 + mb + r) * 4096 + cn] = acc[rg][r];
  }

  __syncthreads();  // drain stores (and junk staging DMAs)
  __shared__ unsigned oldv;
  if (t == 0)
    oldv = __hip_atomic_fetch_add(&counters[nt], 1u, __ATOMIC_ACQ_REL, __HIP_MEMORY_SCOPE_AGENT);
  __syncthreads();
  if (oldv != SPLITS - 1) return;

  // ---- finisher: reduce splits + LSTM cell for this tile's 16 hid cols ----
  (void)__hip_atomic_load(&counters[nt], __ATOMIC_ACQUIRE, __HIP_MEMORY_SCOPE_AGENT);
  const int fc = t & 15, fm = t >> 4;
  const int nh = nt * 16 + fc;
  const f32x4 bv = *reinterpret_cast<const f32x4*>(&bias[nh * 4]);
#pragma unroll
  for (int p = 0; p < 8; ++p) {
    int m = fm + p * 16;
    size_t gi0 = (size_t)m * 4096 + nh * 4;
    f32x4 s = *reinterpret_cast<const f32x4*>(&partials[gi0]);
#pragma unroll
    for (int q = 1; q < SPLITS; ++q)
      s += *reinterpret_cast<const f32x4*>(&partials[gi0 + (size_t)q * BATCH * 4096]);
    float gi = sigm(s[0] + bv[0]);
    float gf = sigm(s[1] + bv[1]);
    float gg = tanhf(s[2] + bv[2]);
    float go = sigm(s[3] + bv[3]);
    size_t sidx = (size_t)m * HID + nh;
    float cn2 = gf * c[sidx] + gi * gg;
    c[sidx] = cn2;
    float h = go * tanhf(cn2);
    unsigned short h16 = f2h(h);
    ohh[sidx] = h16;
    ohl[sidx] = f2h(h - h2f(h16));
  }
  __syncthreads();
  if (t == 0)
    __hip_atomic_store(&counters[nt], 0u, __ATOMIC_RELAXED, __HIP_MEMORY_SCOPE_AGENT);
}

// Decoder: out = h2 @ w_dec^T + b_dec. 4 waves split K, LDS reduce. fp16x2.
__global__ __launch_bounds__(256) void dec_k(
    const unsigned short* __restrict__ hhi, const unsigned short* __restrict__ hlo,
    const unsigned short* __restrict__ wdh,
    const float* __restrict__ bd,
    float* __restrict__ outp,
    unsigned short* __restrict__ fxhi, unsigned short* __restrict__ fxlo)
{
  const int wave = threadIdx.x >> 6, lane = threadIdx.x & 63;
  const int n0 = ((int)blockIdx.x % 11) * 16;
  const int m0 = ((int)blockIdx.x / 11) * 16;
  const int row = lane & 15, kg = lane >> 4;
  f32x4 acc = {0.f, 0.f, 0.f, 0.f};
  const unsigned short* pah = hhi + (size_t)(m0 + row) * HID + kg * 8 + wave * 256;
  const unsigned short* pal = hlo + (size_t)(m0 + row) * HID + kg * 8 + wave * 256;
  const unsigned short* pbh = wdh + (size_t)(n0 + row) * HID + kg * 8 + wave * 256;
#pragma unroll
  for (int kk = 0; kk < 8; ++kk) {
    int off = kk * 32;
    f16x8 a1 = ld8(pah + off), a2 = ld8(pal + off);
    f16x8 b1 = ld8(pbh + off);
    acc = __builtin_amdgcn_mfma_f32_16x16x32_f16(a1, b1, acc, 0, 0, 0);
    acc = __builtin_amdgcn_mfma_f32_16x16x32_f16(a2, b1, acc, 0, 0, 0);
  }
  __shared__ f32x4 red[4][64];
  if (wave) red[wave][lane] = acc;
  __syncthreads();
  if (wave == 0) {
    acc += red[1][lane];
    acc += red[2][lane];
    acc += red[3][lane];
    const int col = lane & 15, rg = lane >> 4;
#pragma unroll
    for (int r = 0; r < 4; ++r) {
      int m = m0 + rg * 4 + r;
      int n = n0 + col;
      if (n < OUTN) {
        float v = acc[r] + bd[n];
        if (outp) outp[(size_t)m * (GENF * OUTN) + n] = v;
        unsigned short vh = f2h(v);
        fxhi[(size_t)m * INPAD + n] = vh;
        fxlo[(size_t)m * INPAD + n] = f2h(v - h2f(vh));
      }
    }
  }
}

// ---- prep kernels ----
// LSTM weight: src [4096 gate-major][C] f32 -> dst rows permuted (nh*4+g), cols
// at [co, co+Cpad) of a [4096][dstride] fp16 buffer.
__global__ void cvt_w_k(const float* __restrict__ src, unsigned short* __restrict__ w16,
                        int C, int Cpad, int co, int dstride)
{
  int idx = blockIdx.x * 256 + threadIdx.x;
  if (idx >= 4096 * Cpad) return;
  int r = idx / Cpad, cc = idx - r * Cpad;
  float v = (cc < C) ? src[(size_t)r * C + cc] : 0.f;
  int rp = (r & 1023) * 4 + (r >> 10);
  w16[(size_t)rp * dstride + co + cc] = f2h(v);
}

__global__ void cvt_wd_k(const float* __restrict__ src, unsigned short* __restrict__ w16,
                         int R, int C, int Rp, int Cp)
{
  int idx = blockIdx.x * 256 + threadIdx.x;
  if (idx >= Rp * Cp) return;
  int r = idx / Cp, c2 = idx - r * Cp;
  float v = (r < R && c2 < C) ? src[(size_t)r * C + c2] : 0.f;
  w16[idx] = f2h(v);
}

__global__ void bias_perm_k(const float* __restrict__ a, const float* __restrict__ b,
                            float* __restrict__ dst)
{
  int i = blockIdx.x * 256 + threadIdx.x;
  if (i < 4096) dst[(i & 1023) * 4 + (i >> 10)] = a[i] + b[i];
}

__global__ void biaspad_k(const float* __restrict__ a, float* __restrict__ dst, int n, int np)
{
  int i = blockIdx.x * 256 + threadIdx.x;
  if (i < np) dst[i] = (i < n) ? a[i] : 0.f;
}

// initial_seq [B][T][IN] fp32 -> xcond hi/lo [T][B][INPAD] fp16 (zero-padded cols)
__global__ void xcond_k(const float* __restrict__ seq, unsigned short* __restrict__ xhi,
                        unsigned short* __restrict__ xlo)
{
  int idx = blockIdx.x * 256 + threadIdx.x;
  const int total = TCOND * BATCH * INPAD;
  if (idx >= total) return;
  int t = idx / (BATCH * INPAD);
  int rem = idx - t * (BATCH * INPAD);
  int b = rem / INPAD;
  int k = rem - b * INPAD;
  float v = (k < INP) ? seq[((size_t)b * TCOND + t) * INP + k] : 0.f;
  unsigned short h = f2h(v);
  xhi[idx] = h;
  xlo[idx] = f2h(v - h2f(h));
}

extern "C" void kernel_launch(void* const* d_in, const int* in_sizes, int n_in,
                              void* d_out, int out_size, void* d_ws, size_t ws_size,
                              hipStream_t stream)
{
  (void)in_sizes; (void)n_in; (void)out_size;
  const float* seq   = (const float*)d_in[0];
  const float* w_ih1 = (const float*)d_in[2];
  const float* w_hh1 = (const float*)d_in[3];
  const float* b_ih1 = (const float*)d_in[4];
  const float* b_hh1 = (const float*)d_in[5];
  const float* w_ih2 = (const float*)d_in[6];
  const float* w_hh2 = (const float*)d_in[7];
  const float* b_ih2 = (const float*)d_in[8];
  const float* b_hh2 = (const float*)d_in[9];
  const float* w_ih3 = (const float*)d_in[10];
  const float* w_hh3 = (const float*)d_in[11];
  const float* b_ih3 = (const float*)d_in[12];
  const float* b_hh3 = (const float*)d_in[13];
  const float* w_dec = (const float*)d_in[14];
  const float* b_dec = (const float*)d_in[15];
  float* out = (float*)d_out;

  char* ws = (char*)d_ws;
  size_t off = 0;
  auto alloc = [&](size_t bytes) -> char* {
    off = (off + 255) & ~(size_t)255;
    char* p = ws + off;
    off += bytes;
    return p;
  };
  auto us = [&](size_t n) { return (unsigned short*)alloc(n * 2); };
  auto fl = [&](size_t n) { return (float*)alloc(n * 4); };

  const int K1P = 1536;        // padded: 192 + 1024 = 1216 -> 1536 (NK=48, nit=6 even)
  const int NK1R = 38;         // real chunks (6 x + 32 h)
  const int K2 = 2 * HID;      // 2048 (NK=64, nit=8)
  unsigned short *W1 = us((size_t)4096 * K1P);
  unsigned short *W2 = us((size_t)4096 * K2);
  unsigned short *W3 = us((size_t)4096 * K2);
  unsigned short *wd = us((size_t)OUTPAD * HID);
  float *b1 = fl(4096), *b2 = fl(4096), *b3 = fl(4096), *bd = fl(OUTPAD);
  unsigned short *xch = us((size_t)TCOND * BATCH * INPAD), *xcl = us((size_t)TCOND * BATCH * INPAD);
  float* partials = fl((size_t)SPLITS * BATCH * 4096);

  size_t state_beg = (off + 255) & ~(size_t)255;
  float *c0 = fl((size_t)BATCH * HID), *c1 = fl((size_t)BATCH * HID), *c2 = fl((size_t)BATCH * HID);
  unsigned short* Hh[3][2];
  unsigned short* Hl[3][2];
  for (int L = 0; L < 3; ++L)
    for (int p = 0; p < 2; ++p) {
      Hh[L][p] = us((size_t)BATCH * HID);
      Hl[L][p] = us((size_t)BATCH * HID);
    }
  unsigned short *fxh = us((size_t)BATCH * INPAD), *fxl = us((size_t)BATCH * INPAD);
  unsigned* counters = (unsigned*)alloc(TILES * 4);
  size_t state_end = off;

  if (off > ws_size) return;  // scratch too small; fail visibly

  hipMemsetAsync(ws + state_beg, 0, state_end - state_beg, stream);
  // zero W1 pad columns (1216..1535) — memset whole W1 before cvt fills real cols
  hipMemsetAsync(W1, 0, (size_t)4096 * K1P * 2, stream);

  // ---- weight / input prep ----
  auto cw = [&](const float* s, unsigned short* w, int C, int Cpad, int co, int ds2) {
    int n = 4096 * Cpad;
    cvt_w_k<<<(n + 255) / 256, 256, 0, stream>>>(s, w, C, Cpad, co, ds2);
  };
  cw(w_ih1, W1, INP, INPAD, 0, K1P);
  cw(w_hh1, W1, HID, HID, INPAD, K1P);
  cw(w_ih2, W2, HID, HID, 0, K2);
  cw(w_hh2, W2, HID, HID, HID, K2);
  cw(w_ih3, W3, HID, HID, 0, K2);
  cw(w_hh3, W3, HID, HID, HID, K2);
  {
    int n = OUTPAD * HID;
    cvt_wd_k<<<(n + 255) / 256, 256, 0, stream>>>(w_dec, wd, OUTN, HID, OUTPAD, HID);
  }
  bias_perm_k<<<16, 256, 0, stream>>>(b_ih1, b_hh1, b1);
  bias_perm_k<<<16, 256, 0, stream>>>(b_ih2, b_hh2, b2);
  bias_perm_k<<<16, 256, 0, stream>>>(b_ih3, b_hh3, b3);
  biaspad_k<<<1, 256, 0, stream>>>(b_dec, bd, OUTN, OUTPAD);
  {
    int n = TCOND * BATCH * INPAD;
    xcond_k<<<(n + 255) / 256, 256, 0, stream>>>(seq, xch, xcl);
  }

  // ---- recurrent loop ----
  for (int s = 0; s < TCOND + GENF; ++s) {
    const unsigned short *xh, *xl;
    if (s < TCOND) {
      xh = xch + (size_t)s * BATCH * INPAD;
      xl = xcl + (size_t)s * BATCH * INPAD;
    } else {
      xh = fxh;
      xl = fxl;
    }
    int pp = s & 1, np = pp ^ 1;
    lstm_gemm_k<<<TILES * SPLITS, 256, 0, stream>>>(xh, xl, INPAD, INPAD / 32,
        Hh[0][pp], Hl[0][pp], W1, K1P, K1P / 32, NK1R, b1, c0,
        Hh[0][np], Hl[0][np], partials, counters);
    lstm_gemm_k<<<TILES * SPLITS, 256, 0, stream>>>(Hh[0][np], Hl[0][np], HID, HID / 32,
        Hh[1][pp], Hl[1][pp], W2, K2, K2 / 32, K2 / 32, b2, c1,
        Hh[1][np], Hl[1][np], partials, counters);
    lstm_gemm_k<<<TILES * SPLITS, 256, 0, stream>>>(Hh[1][np], Hl[1][np], HID, HID / 32,
        Hh[2][pp], Hl[2][pp], W3, K2, K2 / 32, K2 / 32, b3, c2,
        Hh[2][np], Hl[2][np], partials, counters);
    if (s == TCOND - 1) {
      dec_k<<<88, 256, 0, stream>>>(Hh[2][np], Hl[2][np], wd, bd,
                                    (float*)nullptr, fxh, fxl);
    } else if (s >= TCOND) {
      dec_k<<<88, 256, 0, stream>>>(Hh[2][np], Hl[2][np], wd, bd,
                                    out + (size_t)(s - TCOND) * OUTN, fxh, fxl);
    }
  }
}

// Round 17
// 14567.004 us; speedup vs baseline: 1.2970x; 1.2074x over previous
//
#include <hip/hip_runtime.h>

typedef __attribute__((ext_vector_type(8))) short short8;
typedef __attribute__((ext_vector_type(8))) _Float16 f16x8;
typedef __attribute__((ext_vector_type(4))) float f32x4;

#define GENF 100
#define TCOND 50
#define BATCH 128
#define HID 1024
#define INP 171
#define INPAD 192
#define OUTN 171
#define OUTPAD 176
#define TILES 64
#define PSTR ((size_t)BATCH * 4096)

static __device__ __forceinline__ unsigned short f2h(float f) {
  _Float16 h = (_Float16)f;
  return __builtin_bit_cast(unsigned short, h);
}
static __device__ __forceinline__ float h2f(unsigned short s) {
  return (float)__builtin_bit_cast(_Float16, s);
}
static __device__ __forceinline__ f16x8 ld8(const unsigned short* p) {
  short8 v = *reinterpret_cast<const short8*>(p);
  return __builtin_bit_cast(f16x8, v);
}
static __device__ __forceinline__ float sigm(float x) { return 1.f / (1.f + __expf(-x)); }

// Core split-K GEMM strip (R12/R15-proven): 64 perm-cols of tile nt over chunks
// [beg, beg+nit) (nit even), fp16x2 (A=hi+lo, W single fp16), 3 rotating LDS
// bufs, depth-2 prefetch, counted vmcnt(20). Stores f32 partials to pslot.
// Pad-chunk convention (R15): A STAGING clamps ck>=nkr to chunk 0 (valid reads);
// W loads use ck DIRECTLY and read the zeroed pad columns -> contribution 0.
static __device__ __forceinline__ void core_gemm(
    char* smem, int nt,
    const unsigned short* __restrict__ xh_, const unsigned short* __restrict__ xl_,
    int ldx, int xc,
    const unsigned short* __restrict__ hh_, const unsigned short* __restrict__ hl_,
    const unsigned short* __restrict__ wH, int ldw, int nkr,
    int beg, int nit,
    float* __restrict__ pslot)
{
  const int t = threadIdx.x;
  const int lane = t & 63, wv = t >> 6;
  const int n0 = nt * 64 + wv * 16;
  const int ns = nit >> 1;

  const int r_row = lane & 15, kg = lane >> 4;
  const int rslot = kg ^ (r_row & 3);
  const int srow = t >> 2;
  const size_t bcol = (size_t)(n0 + r_row) * ldw + kg * 8;

  auto stage1 = [&](char* dst, int ck) {
    if (ck >= nkr) ck = 0;  // A staging clamp only (W reads the zero pad cols)
    const unsigned short *sh, *sl;
    int ld, k0;
    if (ck < xc) { sh = xh_; sl = xl_; ld = ldx; k0 = ck * 32; }
    else { sh = hh_; sl = hl_; ld = HID; k0 = (ck - xc) * 32; }
#pragma unroll
    for (int j = 0; j < 2; ++j) {
      int rowp = j * 64 + srow;
      int slot = (t & 3) ^ (rowp & 3);
      const unsigned short* gh = sh + (size_t)rowp * ld + k0 + slot * 8;
      const unsigned short* gl = sl + (size_t)rowp * ld + k0 + slot * 8;
      char* dh = dst + j * 4096 + wv * 1024;
      char* dl = dst + 8192 + j * 4096 + wv * 1024;
      __builtin_amdgcn_global_load_lds((const __attribute__((address_space(1))) void*)gh,
                                       (__attribute__((address_space(3))) void*)dh, 16, 0, 0);
      __builtin_amdgcn_global_load_lds((const __attribute__((address_space(1))) void*)gl,
                                       (__attribute__((address_space(3))) void*)dl, 16, 0, 0);
    }
  };

  f32x4 zz = {0.f, 0.f, 0.f, 0.f};
  f32x4 acc[8] = {zz, zz, zz, zz, zz, zz, zz, zz};

  char* bA = smem;
  char* bB = smem + 32768;
  char* bC = smem + 65536;

  stage1(bA, beg);
  stage1(bA + 16384, beg + 1);
  f16x8 b0h0 = ld8(wH + bcol + (size_t)(beg + 0) * 32);
  f16x8 b0h1 = ld8(wH + bcol + (size_t)(beg + 1) * 32);
  __builtin_amdgcn_sched_barrier(0);
  stage1(bB, beg + 2);
  stage1(bB + 16384, beg + 3);
  f16x8 b1h0 = ld8(wH + bcol + (size_t)(beg + 2) * 32);
  f16x8 b1h1 = ld8(wH + bcol + (size_t)(beg + 3) * 32);
  __builtin_amdgcn_sched_barrier(0);

  for (int i = 0; i < ns; ++i) {
    int ck = beg + 2 * i + 4;
    if (ck >= beg + nit) ck = beg;  // junk tail (uniform counts, unused)
    stage1(bC, ck);
    stage1(bC + 16384, ck + 1);
    f16x8 b2h0 = ld8(wH + bcol + (size_t)ck * 32);        // pad chunks: zero cols
    f16x8 b2h1 = ld8(wH + bcol + (size_t)(ck + 1) * 32);
    __builtin_amdgcn_sched_barrier(0);

    asm volatile("s_waitcnt vmcnt(20)" ::: "memory");
    __builtin_amdgcn_s_barrier();
    __builtin_amdgcn_sched_barrier(0);

#pragma unroll
    for (int ch = 0; ch < 2; ++ch) {
      f16x8 ah[8], al[8];
#pragma unroll
      for (int rg = 0; rg < 8; ++rg) {
        int ro = ch * 16384 + (rg * 16 + r_row) * 64 + rslot * 16;
        ah[rg] = *reinterpret_cast<const f16x8*>(bA + ro);
        al[rg] = *reinterpret_cast<const f16x8*>(bA + ro + 8192);
      }
      f16x8 BH = ch ? b0h1 : b0h0;
#pragma unroll
      for (int rg = 0; rg < 8; ++rg)
        acc[rg] = __builtin_amdgcn_mfma_f32_16x16x32_f16(ah[rg], BH, acc[rg], 0, 0, 0);
#pragma unroll
      for (int rg = 0; rg < 8; ++rg)
        acc[rg] = __builtin_amdgcn_mfma_f32_16x16x32_f16(al[rg], BH, acc[rg], 0, 0, 0);
    }
    __builtin_amdgcn_sched_barrier(0);
    __builtin_amdgcn_s_barrier();

    char* tmp = bA; bA = bB; bB = bC; bC = tmp;
    b0h0 = b1h0; b0h1 = b1h1;
    b1h0 = b2h0; b1h1 = b2h1;
  }

  {
    const int cn = n0 + r_row;
    const int mb = kg * 4;
#pragma unroll
    for (int rg = 0; rg < 8; ++rg)
#pragma unroll
      for (int r = 0; r < 4; ++r)
        pslot[(size_t)(rg * 16 + mb + r) * 4096 + cn] = acc[rg][r];
  }
}

// Counter-elected finisher: reduce nslots partial slots + bias, fused LSTM cell,
// write h hi/lo (+ optional history copy). Resets counter for reuse.
static __device__ __forceinline__ void fin_cell(
    int nt, int splits, unsigned* __restrict__ cnt,
    const float* __restrict__ pbase, int nslots,
    const float* __restrict__ bias, float* __restrict__ c,
    unsigned short* __restrict__ ohh, unsigned short* __restrict__ ohl,
    unsigned short* __restrict__ histh, unsigned short* __restrict__ histl)
{
  const int t = threadIdx.x;
  __syncthreads();  // drain partial stores + junk staging
  __shared__ unsigned oldv;
  if (t == 0)
    oldv = __hip_atomic_fetch_add(&cnt[nt], 1u, __ATOMIC_ACQ_REL, __HIP_MEMORY_SCOPE_AGENT);
  __syncthreads();
  if (oldv != splits - 1) return;

  (void)__hip_atomic_load(&cnt[nt], __ATOMIC_ACQUIRE, __HIP_MEMORY_SCOPE_AGENT);
  const int fc = t & 15, fm = t >> 4;
  const int nh = nt * 16 + fc;
  const f32x4 bv = *reinterpret_cast<const f32x4*>(&bias[nh * 4]);
#pragma unroll
  for (int p = 0; p < 8; ++p) {
    int m = fm + p * 16;
    size_t gi0 = (size_t)m * 4096 + nh * 4;
    f32x4 s = *reinterpret_cast<const f32x4*>(&pbase[gi0]);
    for (int q = 1; q < nslots; ++q)
      s += *reinterpret_cast<const f32x4*>(&pbase[gi0 + (size_t)q * PSTR]);
    float gi = sigm(s[0] + bv[0]);
    float gf = sigm(s[1] + bv[1]);
    float gg = tanhf(s[2] + bv[2]);
    float go = sigm(s[3] + bv[3]);
    size_t sidx = (size_t)m * HID + nh;
    float cn2 = gf * c[sidx] + gi * gg;
    c[sidx] = cn2;
    float h = go * tanhf(cn2);
    unsigned short h16 = f2h(h);
    unsigned short l16 = f2h(h - h2f(h16));
    ohh[sidx] = h16;
    ohl[sidx] = l16;
    if (histh) { histh[sidx] = h16; histl[sidx] = l16; }
  }
  __syncthreads();
  if (t == 0)
    __hip_atomic_store(&cnt[nt], 0u, __ATOMIC_RELAXED, __HIP_MEMORY_SCOPE_AGENT);
}

struct AP {  // phase A: L1 full (128 blks, splits=2) + L2h (64) + L3h (64)
  const unsigned short *x1h, *x1l; int ldx1, xc1;
  const unsigned short *h1h, *h1l;
  const unsigned short* W1; int ldw1, NK1, nkr1;
  float* p1; unsigned* cnt1; const float* b1; float* c0;
  unsigned short *o1h, *o1l;
  const unsigned short *a2h, *a2l; const unsigned short* W2h_; float* p2;
  const unsigned short *a3h, *a3l; const unsigned short* W3h_; float* p3;
};

__global__ __launch_bounds__(256) void phaseA_k(AP p) {
  __shared__ __align__(16) char smem[98304];
  const int blk = blockIdx.x;
  if (blk < 128) {
    int nt = blk & 63, sp = blk >> 6;
    int nit = p.NK1 >> 1;
    core_gemm(smem, nt, p.x1h, p.x1l, p.ldx1, p.xc1, p.h1h, p.h1l,
              p.W1, p.ldw1, p.nkr1, sp * nit, nit, p.p1 + sp * PSTR);
    fin_cell(nt, 2, p.cnt1, p.p1, 2, p.b1, p.c0, p.o1h, p.o1l,
             (unsigned short*)0, (unsigned short*)0);
  } else if (blk < 192) {
    int nt = blk - 128;
    core_gemm(smem, nt, p.a2h, p.a2l, HID, 32, p.a2h, p.a2l,
              p.W2h_, HID, 32, 0, 32, p.p2 + 4 * PSTR);
  } else {
    int nt = blk - 192;
    core_gemm(smem, nt, p.a3h, p.a3l, HID, 32, p.a3h, p.a3l,
              p.W3h_, HID, 32, 0, 32, p.p3 + 4 * PSTR);
  }
}

struct XP {  // phase B/C: x-part GEMM (splits=4 over K=1024) + finisher(5 slots)
  const unsigned short *ah, *al;
  const unsigned short* Wx;
  float* pb; unsigned* cnt; const float* bias; float* c;
  unsigned short *ohh, *ohl, *histh, *histl;
};

__global__ __launch_bounds__(256) void phaseX_k(XP p) {
  __shared__ __align__(16) char smem[98304];
  const int nt = blockIdx.x & 63, sp = blockIdx.x >> 6;
  core_gemm(smem, nt, p.ah, p.al, HID, 32, p.ah, p.al,
            p.Wx, HID, 32, sp * 8, 8, p.pb + sp * PSTR);
  fin_cell(nt, 4, p.cnt, p.pb, 5, p.bias, p.c, p.ohh, p.ohl, p.histh, p.histl);
}

// Batched decoder over history: out[b][t][:] = hist[t*128+b] @ wd^T + bd.
__global__ __launch_bounds__(256) void decb_k(
    const unsigned short* __restrict__ histh, const unsigned short* __restrict__ histl,
    const unsigned short* __restrict__ wdh, const float* __restrict__ bd,
    float* __restrict__ outp)
{
  const int wave = threadIdx.x >> 6, lane = threadIdx.x & 63;
  const int n0 = ((int)blockIdx.x % 11) * 16;
  const int m0 = ((int)blockIdx.x / 11) * 16;
  const int row = lane & 15, kg = lane >> 4;
  f32x4 acc = {0.f, 0.f, 0.f, 0.f};
  const unsigned short* pah = histh + (size_t)(m0 + row) * HID + kg * 8 + wave * 256;
  const unsigned short* pal = histl + (size_t)(m0 + row) * HID + kg * 8 + wave * 256;
  const unsigned short* pbh = wdh + (size_t)(n0 + row) * HID + kg * 8 + wave * 256;
#pragma unroll
  for (int kk = 0; kk < 8; ++kk) {
    int off = kk * 32;
    f16x8 a1 = ld8(pah + off), a2 = ld8(pal + off);
    f16x8 b1 = ld8(pbh + off);
    acc = __builtin_amdgcn_mfma_f32_16x16x32_f16(a1, b1, acc, 0, 0, 0);
    acc = __builtin_amdgcn_mfma_f32_16x16x32_f16(a2, b1, acc, 0, 0, 0);
  }
  __shared__ f32x4 red[4][64];
  if (wave) red[wave][lane] = acc;
  __syncthreads();
  if (wave == 0) {
    acc += red[1][lane];
    acc += red[2][lane];
    acc += red[3][lane];
    const int col = lane & 15, rg = lane >> 4;
#pragma unroll
    for (int r = 0; r < 4; ++r) {
      int m = m0 + rg * 4 + r;
      int n = n0 + col;
      if (n < OUTN) {
        int tt = m >> 7, b = m & 127;
        outp[(size_t)b * (GENF * OUTN) + (size_t)tt * OUTN + n] = acc[r] + bd[n];
      }
    }
  }
}

// ---- prep kernels ----
// LSTM weight: [4096 gate-major][C] f32 -> rows permuted (nh*4+g), cols at
// [co, co+Cpad) of [4096][dstride] fp16.
__global__ void cvt_w_k(const float* __restrict__ src, unsigned short* __restrict__ w16,
                        int C, int Cpad, int co, int dstride)
{
  int idx = blockIdx.x * 256 + threadIdx.x;
  if (idx >= 4096 * Cpad) return;
  int r = idx / Cpad, cc = idx - r * Cpad;
  float v = (cc < C) ? src[(size_t)r * C + cc] : 0.f;
  int rp = (r & 1023) * 4 + (r >> 10);
  w16[(size_t)rp * dstride + co + cc] = f2h(v);
}

// plain fp16 cvt with row/col pad (no perm)
__global__ void cvt_plain_k(const float* __restrict__ src, unsigned short* __restrict__ w16,
                            int R, int C, int Rp, int Cp)
{
  int idx = blockIdx.x * 256 + threadIdx.x;
  if (idx >= Rp * Cp) return;
  int r = idx / Cp, c2 = idx - r * Cp;
  float v = (r < R && c2 < C) ? src[(size_t)r * C + c2] : 0.f;
  w16[idx] = f2h(v);
}

// transposed dec weight: wdt[k][j] = w_dec[j][k], [1024][192] fp16 (pad j>=171 -> 0)
__global__ void cvt_wdt_k(const float* __restrict__ wdec, unsigned short* __restrict__ wdt)
{
  int idx = blockIdx.x * 256 + threadIdx.x;
  if (idx >= 1024 * 192) return;
  int k = idx / 192, j = idx - k * 192;
  float v = (j < OUTN) ? wdec[(size_t)j * HID + k] : 0.f;
  wdt[idx] = f2h(v);
}

// Weff = Wih1 @ Wd : [4096][1024], stored permuted into W1g cols 0..1023 fp16
// (k-space x-part comes FIRST in core_gemm). grid 4096 x 256, K=192 fp16.
__global__ __launch_bounds__(256) void weff_k(
    const unsigned short* __restrict__ wih, const unsigned short* __restrict__ wdt,
    unsigned short* __restrict__ W1g)
{
  const int wave = threadIdx.x >> 6, lane = threadIdx.x & 63;
  const int tile = blockIdx.x * 4 + wave;
  const int m0 = (tile >> 6) * 16;   // 0..4095 (i)
  const int n0 = (tile & 63) * 16;   // 0..1023 (k2)
  const int row = lane & 15, kg = lane >> 4;
  f32x4 acc = {0.f, 0.f, 0.f, 0.f};
  const unsigned short* pa = wih + (size_t)(m0 + row) * 192 + kg * 8;
  const unsigned short* pb = wdt + (size_t)(n0 + row) * 192 + kg * 8;
#pragma unroll
  for (int kk = 0; kk < 6; ++kk) {
    int off = kk * 32;
    f16x8 a = ld8(pa + off);
    f16x8 b = ld8(pb + off);
    acc = __builtin_amdgcn_mfma_f32_16x16x32_f16(a, b, acc, 0, 0, 0);
  }
  const int col = lane & 15, rg = lane >> 4;
#pragma unroll
  for (int r = 0; r < 4; ++r) {
    int i = m0 + rg * 4 + r;
    int k2 = n0 + col;
    int rp = (i & 1023) * 4 + (i >> 10);
    W1g[(size_t)rp * 2048 + k2] = f2h(acc[r]);
  }
}

// beff[rp(i)] = b_ih1[i] + b_hh1[i] + sum_j Wih1[i][j] * b_dec[j]  (fp32)
__global__ void beff_k(const float* __restrict__ wih1, const float* __restrict__ bih,
                       const float* __restrict__ bhh, const float* __restrict__ bdec,
                       float* __restrict__ dst)
{
  int i = blockIdx.x * 256 + threadIdx.x;
  if (i >= 4096) return;
  float a = bih[i] + bhh[i];
  for (int j = 0; j < OUTN; ++j) a += wih1[(size_t)i * OUTN + j] * bdec[j];
  dst[(i & 1023) * 4 + (i >> 10)] = a;
}

__global__ void bias_perm_k(const float* __restrict__ a, const float* __restrict__ b,
                            float* __restrict__ dst)
{
  int i = blockIdx.x * 256 + threadIdx.x;
  if (i < 4096) dst[(i & 1023) * 4 + (i >> 10)] = a[i] + b[i];
}

__global__ void biaspad_k(const float* __restrict__ a, float* __restrict__ dst, int n, int np)
{
  int i = blockIdx.x * 256 + threadIdx.x;
  if (i < np) dst[i] = (i < n) ? a[i] : 0.f;
}

// initial_seq [B][T][IN] fp32 -> xcond hi/lo [T][B][INPAD] fp16
__global__ void xcond_k(const float* __restrict__ seq, unsigned short* __restrict__ xhi,
                        unsigned short* __restrict__ xlo)
{
  int idx = blockIdx.x * 256 + threadIdx.x;
  const int total = TCOND * BATCH * INPAD;
  if (idx >= total) return;
  int t = idx / (BATCH * INPAD);
  int rem = idx - t * (BATCH * INPAD);
  int b = rem / INPAD;
  int k = rem - b * INPAD;
  float v = (k < INP) ? seq[((size_t)b * TCOND + t) * INP + k] : 0.f;
  unsigned short h = f2h(v);
  xhi[idx] = h;
  xlo[idx] = f2h(v - h2f(h));
}

extern "C" void kernel_launch(void* const* d_in, const int* in_sizes, int n_in,
                              void* d_out, int out_size, void* d_ws, size_t ws_size,
                              hipStream_t stream)
{
  (void)in_sizes; (void)n_in; (void)out_size;
  const float* seq   = (const float*)d_in[0];
  const float* w_ih1 = (const float*)d_in[2];
  const float* w_hh1 = (const float*)d_in[3];
  const float* b_ih1 = (const float*)d_in[4];
  const float* b_hh1 = (const float*)d_in[5];
  const float* w_ih2 = (const float*)d_in[6];
  const float* w_hh2 = (const float*)d_in[7];
  const float* b_ih2 = (const float*)d_in[8];
  const float* b_hh2 = (const float*)d_in[9];
  const float* w_ih3 = (const float*)d_in[10];
  const float* w_hh3 = (const float*)d_in[11];
  const float* b_ih3 = (const float*)d_in[12];
  const float* b_hh3 = (const float*)d_in[13];
  const float* w_dec = (const float*)d_in[14];
  const float* b_dec = (const float*)d_in[15];
  float* out = (float*)d_out;

  char* ws = (char*)d_ws;
  size_t off = 0;
  auto alloc = [&](size_t bytes) -> char* {
    off = (off + 255) & ~(size_t)255;
    char* p = ws + off;
    off += bytes;
    return p;
  };
  auto us = [&](size_t n) { return (unsigned short*)alloc(n * 2); };
  auto fl = [&](size_t n) { return (float*)alloc(n * 4); };

  const int K1C = 1536;  // cond L1: 192(x) + 1024(h0) = 1216 -> pad 1536 (NK=48, nkr=38)
  unsigned short* W1c = us((size_t)4096 * K1C);
  unsigned short* W1g = us((size_t)4096 * 2048);  // [0..1023]=Weff, [1024..2047]=Whh1
  unsigned short* W2x = us((size_t)4096 * HID);
  unsigned short* W2h = us((size_t)4096 * HID);
  unsigned short* W3x = us((size_t)4096 * HID);
  unsigned short* W3h = us((size_t)4096 * HID);
  unsigned short* wd = us((size_t)OUTPAD * HID);
  unsigned short* wih1f = us((size_t)4096 * 192);  // plain fp16 Wih1 (for weff)
  unsigned short* wdt = us((size_t)1024 * 192);    // transposed Wd (for weff)
  float *b1c = fl(4096), *beff = fl(4096), *b2 = fl(4096), *b3 = fl(4096), *bd = fl(OUTPAD);
  unsigned short *xch = us((size_t)TCOND * BATCH * INPAD), *xcl = us((size_t)TCOND * BATCH * INPAD);
  float* pL1 = fl(2 * PSTR);
  float* pL2 = fl(5 * PSTR);
  float* pL3 = fl(5 * PSTR);
  unsigned short* histh = us((size_t)GENF * BATCH * HID);
  unsigned short* histl = us((size_t)GENF * BATCH * HID);

  size_t state_beg = (off + 255) & ~(size_t)255;
  float *c0 = fl((size_t)BATCH * HID), *c1 = fl((size_t)BATCH * HID), *c2 = fl((size_t)BATCH * HID);
  unsigned short* Hh[3][2];
  unsigned short* Hl[3][2];
  for (int L = 0; L < 3; ++L)
    for (int p = 0; p < 2; ++p) {
      Hh[L][p] = us((size_t)BATCH * HID);
      Hl[L][p] = us((size_t)BATCH * HID);
    }
  unsigned* counters = (unsigned*)alloc(192 * 4);  // [0..63] L1, [64..127] L2, [128..191] L3
  size_t state_end = off;

  if (off > ws_size) return;  // scratch too small; fail visibly

  hipMemsetAsync(ws + state_beg, 0, state_end - state_beg, stream);
  // zero pads: W1c pad cols (1216..1535)
  hipMemsetAsync(W1c, 0, (size_t)4096 * K1C * 2, stream);

  // ---- weight / input prep ----
  cvt_w_k<<<(4096 * INPAD + 255) / 256, 256, 0, stream>>>(w_ih1, W1c, INP, INPAD, 0, K1C);
  cvt_w_k<<<(4096 * 1024 + 255) / 256, 256, 0, stream>>>(w_hh1, W1c, HID, HID, INPAD, K1C);
  cvt_w_k<<<(4096 * 1024 + 255) / 256, 256, 0, stream>>>(w_hh1, W1g, HID, HID, 1024, 2048);
  cvt_w_k<<<(4096 * 1024 + 255) / 256, 256, 0, stream>>>(w_ih2, W2x, HID, HID, 0, HID);
  cvt_w_k<<<(4096 * 1024 + 255) / 256, 256, 0, stream>>>(w_hh2, W2h, HID, HID, 0, HID);
  cvt_w_k<<<(4096 * 1024 + 255) / 256, 256, 0, stream>>>(w_ih3, W3x, HID, HID, 0, HID);
  cvt_w_k<<<(4096 * 1024 + 255) / 256, 256, 0, stream>>>(w_hh3, W3h, HID, HID, 0, HID);
  cvt_plain_k<<<(OUTPAD * HID + 255) / 256, 256, 0, stream>>>(w_dec, wd, OUTN, HID, OUTPAD, HID);
  cvt_plain_k<<<(4096 * 192 + 255) / 256, 256, 0, stream>>>(w_ih1, wih1f, 4096, INP, 4096, 192);
  cvt_wdt_k<<<(1024 * 192 + 255) / 256, 256, 0, stream>>>(w_dec, wdt);
  weff_k<<<4096, 256, 0, stream>>>(wih1f, wdt, W1g);
  beff_k<<<16, 256, 0, stream>>>(w_ih1, b_ih1, b_hh1, b_dec, beff);
  bias_perm_k<<<16, 256, 0, stream>>>(b_ih1, b_hh1, b1c);
  bias_perm_k<<<16, 256, 0, stream>>>(b_ih2, b_hh2, b2);
  bias_perm_k<<<16, 256, 0, stream>>>(b_ih3, b_hh3, b3);
  biaspad_k<<<1, 256, 0, stream>>>(b_dec, bd, OUTN, OUTPAD);
  xcond_k<<<(TCOND * BATCH * INPAD + 255) / 256, 256, 0, stream>>>(seq, xch, xcl);

  // ---- recurrent loop: 3 phases per step ----
  for (int s = 0; s < TCOND + GENF; ++s) {
    const int pp = s & 1, np = pp ^ 1;
    AP a;
    if (s < TCOND) {
      a.x1h = xch + (size_t)s * BATCH * INPAD;
      a.x1l = xcl + (size_t)s * BATCH * INPAD;
      a.ldx1 = INPAD; a.xc1 = INPAD / 32;
      a.W1 = W1c; a.ldw1 = K1C; a.NK1 = K1C / 32; a.nkr1 = 38;
      a.b1 = b1c;
    } else {
      a.x1h = Hh[2][pp]; a.x1l = Hl[2][pp];  // folded decoder input = h2(t-1)
      a.ldx1 = HID; a.xc1 = 32;
      a.W1 = W1g; a.ldw1 = 2048; a.NK1 = 64; a.nkr1 = 64;
      a.b1 = beff;
    }
    a.h1h = Hh[0][pp]; a.h1l = Hl[0][pp];
    a.p1 = pL1; a.cnt1 = counters; a.c0 = c0;
    a.o1h = Hh[0][np]; a.o1l = Hl[0][np];
    a.a2h = Hh[1][pp]; a.a2l = Hl[1][pp]; a.W2h_ = W2h; a.p2 = pL2;
    a.a3h = Hh[2][pp]; a.a3l = Hl[2][pp]; a.W3h_ = W3h; a.p3 = pL3;
    phaseA_k<<<256, 256, 0, stream>>>(a);

    XP b;
    b.ah = Hh[0][np]; b.al = Hl[0][np];
    b.Wx = W2x; b.pb = pL2; b.cnt = counters + 64;
    b.bias = b2; b.c = c1;
    b.ohh = Hh[1][np]; b.ohl = Hl[1][np];
    b.histh = (unsigned short*)0; b.histl = (unsigned short*)0;
    phaseX_k<<<256, 256, 0, stream>>>(b);

    XP cx;
    cx.ah = Hh[1][np]; cx.al = Hl[1][np];
    cx.Wx = W3x; cx.pb = pL3; cx.cnt = counters + 128;
    cx.bias = b3; cx.c = c2;
    cx.ohh = Hh[2][np]; cx.ohl = Hl[2][np];
    if (s >= TCOND) {
      cx.histh = histh + (size_t)(s - TCOND) * BATCH * HID;
      cx.histl = histl + (size_t)(s - TCOND) * BATCH * HID;
    } else {
      cx.histh = (unsigned short*)0; cx.histl = (unsigned short*)0;
    }
    phaseX_k<<<256, 256, 0, stream>>>(cx);
  }

  // ---- batched decoder: all 100 outputs in one GEMM ----
  decb_k<<<(GENF * BATCH / 16) * 11, 256, 0, stream>>>(histh, histl, wd, bd, out);
}

// Round 18
// 14489.209 us; speedup vs baseline: 1.3039x; 1.0054x over previous
//
#include <hip/hip_runtime.h>

typedef __attribute__((ext_vector_type(8))) short short8;
typedef __attribute__((ext_vector_type(8))) _Float16 f16x8;
typedef __attribute__((ext_vector_type(4))) float f32x4;

#define GENF 100
#define TCOND 50
#define BATCH 128
#define HID 1024
#define INP 171
#define INPAD 192
#define OUTN 171
#define OUTPAD 176
#define SPLITS 4
#define TILES 64
#define PSTR ((size_t)BATCH * 4096)

static __device__ __forceinline__ unsigned short f2h(float f) {
  _Float16 h = (_Float16)f;
  return __builtin_bit_cast(unsigned short, h);
}
static __device__ __forceinline__ float h2f(unsigned short s) {
  return (float)__builtin_bit_cast(_Float16, s);
}
static __device__ __forceinline__ f16x8 ld8(const unsigned short* p) {
  short8 v = *reinterpret_cast<const short8*>(p);
  return __builtin_bit_cast(f16x8, v);
}
static __device__ __forceinline__ float sigm(float x) { return 1.f / (1.f + __expf(-x)); }

// Fused LSTM layer: fp16x2 split-K GEMM + counter-elected finisher cell epilogue.
// W is PACKED per (tile, chunk): Wp[nt][ck][64 cols][32 k] fp16 -> each block
// streams ONE contiguous region (4KB/chunk, wave load = 1KB coalesced), fixing
// the 4KB-strided 64B-scatter of the row-major layout (HBM-efficiency fix).
// K-loop: R12-proven 3 rotating LDS bufs, depth-2 prefetch, counted vmcnt(20).
// A staging: chunks ck>=nkr clamp to chunk 0; W pad chunks are zeroed.
__global__ __launch_bounds__(256) void lstm_gemm_k(
    const unsigned short* __restrict__ xh_, const unsigned short* __restrict__ xl_,
    int ldx, int xc,
    const unsigned short* __restrict__ hh_, const unsigned short* __restrict__ hl_,
    const unsigned short* __restrict__ wP, int NKW, int nkr,
    const float* __restrict__ bias,
    float* __restrict__ c,
    unsigned short* __restrict__ ohh, unsigned short* __restrict__ ohl,
    unsigned short* __restrict__ histh, unsigned short* __restrict__ histl,
    float* __restrict__ partials, unsigned* __restrict__ counters)
{
  __shared__ __align__(16) char smem[98304];  // 3 bufs x 2 chunks x (hi 8K + lo 8K)
  const int t = threadIdx.x;
  const int lane = t & 63, wv = t >> 6;
  const int nt = blockIdx.x & (TILES - 1), sp = blockIdx.x >> 6;
  const int n0 = nt * 64 + wv * 16;
  const int nit = NKW / SPLITS;  // even
  const int beg = sp * nit;
  const int ns = nit >> 1;

  const int r_row = lane & 15, kg = lane >> 4;
  const int rslot = kg ^ (r_row & 3);
  const int srow = t >> 2;
  // packed W: lane's base within a chunk; chunk stride = 2048 elements (4KB)
  const unsigned short* wlane = wP + ((size_t)nt * NKW) * 2048
                                + (wv * 16 + r_row) * 32 + kg * 8;

  auto stage1 = [&](char* dst, int ck) {
    if (ck >= nkr) ck = 0;  // A staging clamp only (W pad chunks are zeroed)
    const unsigned short *sh, *sl;
    int ld, k0;
    if (ck < xc) { sh = xh_; sl = xl_; ld = ldx; k0 = ck * 32; }
    else { sh = hh_; sl = hl_; ld = HID; k0 = (ck - xc) * 32; }
#pragma unroll
    for (int j = 0; j < 2; ++j) {
      int rowp = j * 64 + srow;
      int slot = (t & 3) ^ (rowp & 3);
      const unsigned short* gh = sh + (size_t)rowp * ld + k0 + slot * 8;
      const unsigned short* gl = sl + (size_t)rowp * ld + k0 + slot * 8;
      char* dh = dst + j * 4096 + wv * 1024;
      char* dl = dst + 8192 + j * 4096 + wv * 1024;
      __builtin_amdgcn_global_load_lds((const __attribute__((address_space(1))) void*)gh,
                                       (__attribute__((address_space(3))) void*)dh, 16, 0, 0);
      __builtin_amdgcn_global_load_lds((const __attribute__((address_space(1))) void*)gl,
                                       (__attribute__((address_space(3))) void*)dl, 16, 0, 0);
    }
  };

  f32x4 zz = {0.f, 0.f, 0.f, 0.f};
  f32x4 acc[8] = {zz, zz, zz, zz, zz, zz, zz, zz};

  char* bA = smem;
  char* bB = smem + 32768;
  char* bC = smem + 65536;

  stage1(bA, beg);
  stage1(bA + 16384, beg + 1);
  f16x8 b0h0 = ld8(wlane + (size_t)(beg + 0) * 2048);
  f16x8 b0h1 = ld8(wlane + (size_t)(beg + 1) * 2048);
  __builtin_amdgcn_sched_barrier(0);
  stage1(bB, beg + 2);
  stage1(bB + 16384, beg + 3);
  f16x8 b1h0 = ld8(wlane + (size_t)(beg + 2) * 2048);
  f16x8 b1h1 = ld8(wlane + (size_t)(beg + 3) * 2048);
  __builtin_amdgcn_sched_barrier(0);

  for (int i = 0; i < ns; ++i) {
    int ck = beg + 2 * i + 4;
    if (ck >= beg + nit) ck = beg;  // junk tail (uniform counts, unused)
    stage1(bC, ck);
    stage1(bC + 16384, ck + 1);
    f16x8 b2h0 = ld8(wlane + (size_t)ck * 2048);
    f16x8 b2h1 = ld8(wlane + (size_t)(ck + 1) * 2048);
    __builtin_amdgcn_sched_barrier(0);

    asm volatile("s_waitcnt vmcnt(20)" ::: "memory");
    __builtin_amdgcn_s_barrier();
    __builtin_amdgcn_sched_barrier(0);

#pragma unroll
    for (int ch = 0; ch < 2; ++ch) {
      f16x8 ah[8], al[8];
#pragma unroll
      for (int rg = 0; rg < 8; ++rg) {
        int ro = ch * 16384 + (rg * 16 + r_row) * 64 + rslot * 16;
        ah[rg] = *reinterpret_cast<const f16x8*>(bA + ro);
        al[rg] = *reinterpret_cast<const f16x8*>(bA + ro + 8192);
      }
      f16x8 BH = ch ? b0h1 : b0h0;
#pragma unroll
      for (int rg = 0; rg < 8; ++rg)
        acc[rg] = __builtin_amdgcn_mfma_f32_16x16x32_f16(ah[rg], BH, acc[rg], 0, 0, 0);
#pragma unroll
      for (int rg = 0; rg < 8; ++rg)
        acc[rg] = __builtin_amdgcn_mfma_f32_16x16x32_f16(al[rg], BH, acc[rg], 0, 0, 0);
    }
    __builtin_amdgcn_sched_barrier(0);
    __builtin_amdgcn_s_barrier();

    char* tmp = bA; bA = bB; bB = bC; bC = tmp;
    b0h0 = b1h0; b0h1 = b1h1;
    b1h0 = b2h0; b1h1 = b2h1;
  }

  // ---- store split partials ----
  {
    float* pb = partials + (size_t)sp * PSTR;
    const int cn = n0 + r_row;
    const int mb = kg * 4;
#pragma unroll
    for (int rg = 0; rg < 8; ++rg)
#pragma unroll
      for (int r = 0; r < 4; ++r)
        pb[(size_t)(rg * 16 + mb + r) * 4096 + cn] = acc[rg][r];
  }

  __syncthreads();  // drain stores + junk staging
  __shared__ unsigned oldv;
  if (t == 0)
    oldv = __hip_atomic_fetch_add(&counters[nt], 1u, __ATOMIC_ACQ_REL, __HIP_MEMORY_SCOPE_AGENT);
  __syncthreads();
  if (oldv != SPLITS - 1) return;

  // ---- finisher: reduce splits + LSTM cell for this tile's 16 hid cols ----
  (void)__hip_atomic_load(&counters[nt], __ATOMIC_ACQUIRE, __HIP_MEMORY_SCOPE_AGENT);
  const int fc = t & 15, fm = t >> 4;
  const int nh = nt * 16 + fc;
  const f32x4 bv = *reinterpret_cast<const f32x4*>(&bias[nh * 4]);
#pragma unroll
  for (int p = 0; p < 8; ++p) {
    int m = fm + p * 16;
    size_t gi0 = (size_t)m * 4096 + nh * 4;
    f32x4 s = *reinterpret_cast<const f32x4*>(&partials[gi0]);
#pragma unroll
    for (int q = 1; q < SPLITS; ++q)
      s += *reinterpret_cast<const f32x4*>(&partials[gi0 + (size_t)q * PSTR]);
    float gi = sigm(s[0] + bv[0]);
    float gf = sigm(s[1] + bv[1]);
    float gg = tanhf(s[2] + bv[2]);
    float go = sigm(s[3] + bv[3]);
    size_t sidx = (size_t)m * HID + nh;
    float cn2 = gf * c[sidx] + gi * gg;
    c[sidx] = cn2;
    float h = go * tanhf(cn2);
    unsigned short h16 = f2h(h);
    unsigned short l16 = f2h(h - h2f(h16));
    ohh[sidx] = h16;
    ohl[sidx] = l16;
    if (histh) { histh[sidx] = h16; histl[sidx] = l16; }
  }
  __syncthreads();
  if (t == 0)
    __hip_atomic_store(&counters[nt], 0u, __ATOMIC_RELAXED, __HIP_MEMORY_SCOPE_AGENT);
}

// Batched decoder over history: out[b][t][:] = hist[t*128+b] @ wd^T + bd.
__global__ __launch_bounds__(256) void decb_k(
    const unsigned short* __restrict__ histh, const unsigned short* __restrict__ histl,
    const unsigned short* __restrict__ wdh, const float* __restrict__ bd,
    float* __restrict__ outp)
{
  const int wave = threadIdx.x >> 6, lane = threadIdx.x & 63;
  const int n0 = ((int)blockIdx.x % 11) * 16;
  const int m0 = ((int)blockIdx.x / 11) * 16;
  const int row = lane & 15, kg = lane >> 4;
  f32x4 acc = {0.f, 0.f, 0.f, 0.f};
  const unsigned short* pah = histh + (size_t)(m0 + row) * HID + kg * 8 + wave * 256;
  const unsigned short* pal = histl + (size_t)(m0 + row) * HID + kg * 8 + wave * 256;
  const unsigned short* pbh = wdh + (size_t)(n0 + row) * HID + kg * 8 + wave * 256;
#pragma unroll
  for (int kk = 0; kk < 8; ++kk) {
    int off = kk * 32;
    f16x8 a1 = ld8(pah + off), a2 = ld8(pal + off);
    f16x8 b1 = ld8(pbh + off);
    acc = __builtin_amdgcn_mfma_f32_16x16x32_f16(a1, b1, acc, 0, 0, 0);
    acc = __builtin_amdgcn_mfma_f32_16x16x32_f16(a2, b1, acc, 0, 0, 0);
  }
  __shared__ f32x4 red[4][64];
  if (wave) red[wave][lane] = acc;
  __syncthreads();
  if (wave == 0) {
    acc += red[1][lane];
    acc += red[2][lane];
    acc += red[3][lane];
    const int col = lane & 15, rg = lane >> 4;
#pragma unroll
    for (int r = 0; r < 4; ++r) {
      int m = m0 + rg * 4 + r;
      int n = n0 + col;
      if (n < OUTN) {
        int tt = m >> 7, b = m & 127;
        outp[(size_t)b * (GENF * OUTN) + (size_t)tt * OUTN + n] = acc[r] + bd[n];
      }
    }
  }
}

// ---- prep kernels ----
// LSTM weight -> PACKED: src [4096 gate-major rows][C] f32; perm row rp=(r&1023)*4+(r>>10);
// dst[((nt*NKW + ck0 + cc/32)*64 + (rp&63))*32 + cc%32] fp16, nt = rp>>6.
__global__ void cvt_w_pack_k(const float* __restrict__ src, unsigned short* __restrict__ dst,
                             int C, int Cpad, int ck0, int NKW)
{
  int idx = blockIdx.x * 256 + threadIdx.x;
  if (idx >= 4096 * Cpad) return;
  int r = idx / Cpad, cc = idx - r * Cpad;
  float v = (cc < C) ? src[(size_t)r * C + cc] : 0.f;
  int rp = (r & 1023) * 4 + (r >> 10);
  int nt = rp >> 6, nc = rp & 63;
  int ck = ck0 + (cc >> 5), kk = cc & 31;
  dst[(((size_t)nt * NKW + ck) * 64 + nc) * 32 + kk] = f2h(v);
}

// plain fp16 cvt with row/col pad (no perm)
__global__ void cvt_plain_k(const float* __restrict__ src, unsigned short* __restrict__ w16,
                            int R, int C, int Rp, int Cp)
{
  int idx = blockIdx.x * 256 + threadIdx.x;
  if (idx >= Rp * Cp) return;
  int r = idx / Cp, c2 = idx - r * Cp;
  float v = (r < R && c2 < C) ? src[(size_t)r * C + c2] : 0.f;
  w16[idx] = f2h(v);
}

// transposed dec weight: wdt[k][j] = w_dec[j][k], [1024][192] fp16 (pad j>=171 -> 0)
__global__ void cvt_wdt_k(const float* __restrict__ wdec, unsigned short* __restrict__ wdt)
{
  int idx = blockIdx.x * 256 + threadIdx.x;
  if (idx >= 1024 * 192) return;
  int k = idx / 192, j = idx - k * 192;
  float v = (j < OUTN) ? wdec[(size_t)j * HID + k] : 0.f;
  wdt[idx] = f2h(v);
}

// Weff = Wih1 @ Wd : [4096 perm rows][1024], written PACKED into W1g chunks 0..31.
__global__ __launch_bounds__(256) void weff_k(
    const unsigned short* __restrict__ wih, const unsigned short* __restrict__ wdt,
    unsigned short* __restrict__ W1g)
{
  const int wave = threadIdx.x >> 6, lane = threadIdx.x & 63;
  const int tile = blockIdx.x * 4 + wave;
  const int m0 = (tile >> 6) * 16;   // i
  const int n0 = (tile & 63) * 16;   // k2
  const int row = lane & 15, kg = lane >> 4;
  f32x4 acc = {0.f, 0.f, 0.f, 0.f};
  const unsigned short* pa = wih + (size_t)(m0 + row) * 192 + kg * 8;
  const unsigned short* pb = wdt + (size_t)(n0 + row) * 192 + kg * 8;
#pragma unroll
  for (int kk = 0; kk < 6; ++kk) {
    int off = kk * 32;
    f16x8 a = ld8(pa + off);
    f16x8 b = ld8(pb + off);
    acc = __builtin_amdgcn_mfma_f32_16x16x32_f16(a, b, acc, 0, 0, 0);
  }
  const int col = lane & 15, rg = lane >> 4;
#pragma unroll
  for (int r = 0; r < 4; ++r) {
    int i = m0 + rg * 4 + r;
    int k2 = n0 + col;
    int rp = (i & 1023) * 4 + (i >> 10);
    int nt = rp >> 6, nc = rp & 63;
    int ck = k2 >> 5, kk2 = k2 & 31;
    W1g[(((size_t)nt * 64 + ck) * 64 + nc) * 32 + kk2] = f2h(acc[r]);
  }
}

// beff[rp(i)] = b_ih1[i] + b_hh1[i] + sum_j Wih1[i][j] * b_dec[j]  (fp32)
__global__ void beff_k(const float* __restrict__ wih1, const float* __restrict__ bih,
                       const float* __restrict__ bhh, const float* __restrict__ bdec,
                       float* __restrict__ dst)
{
  int i = blockIdx.x * 256 + threadIdx.x;
  if (i >= 4096) return;
  float a = bih[i] + bhh[i];
  for (int j = 0; j < OUTN; ++j) a += wih1[(size_t)i * OUTN + j] * bdec[j];
  dst[(i & 1023) * 4 + (i >> 10)] = a;
}

__global__ void bias_perm_k(const float* __restrict__ a, const float* __restrict__ b,
                            float* __restrict__ dst)
{
  int i = blockIdx.x * 256 + threadIdx.x;
  if (i < 4096) dst[(i & 1023) * 4 + (i >> 10)] = a[i] + b[i];
}

__global__ void biaspad_k(const float* __restrict__ a, float* __restrict__ dst, int n, int np)
{
  int i = blockIdx.x * 256 + threadIdx.x;
  if (i < np) dst[i] = (i < n) ? a[i] : 0.f;
}

// initial_seq [B][T][IN] fp32 -> xcond hi/lo [T][B][INPAD] fp16
__global__ void xcond_k(const float* __restrict__ seq, unsigned short* __restrict__ xhi,
                        unsigned short* __restrict__ xlo)
{
  int idx = blockIdx.x * 256 + threadIdx.x;
  const int total = TCOND * BATCH * INPAD;
  if (idx >= total) return;
  int t = idx / (BATCH * INPAD);
  int rem = idx - t * (BATCH * INPAD);
  int b = rem / INPAD;
  int k = rem - b * INPAD;
  float v = (k < INP) ? seq[((size_t)b * TCOND + t) * INP + k] : 0.f;
  unsigned short h = f2h(v);
  xhi[idx] = h;
  xlo[idx] = f2h(v - h2f(h));
}

extern "C" void kernel_launch(void* const* d_in, const int* in_sizes, int n_in,
                              void* d_out, int out_size, void* d_ws, size_t ws_size,
                              hipStream_t stream)
{
  (void)in_sizes; (void)n_in; (void)out_size;
  const float* seq   = (const float*)d_in[0];
  const float* w_ih1 = (const float*)d_in[2];
  const float* w_hh1 = (const float*)d_in[3];
  const float* b_ih1 = (const float*)d_in[4];
  const float* b_hh1 = (const float*)d_in[5];
  const float* w_ih2 = (const float*)d_in[6];
  const float* w_hh2 = (const float*)d_in[7];
  const float* b_ih2 = (const float*)d_in[8];
  const float* b_hh2 = (const float*)d_in[9];
  const float* w_ih3 = (const float*)d_in[10];
  const float* w_hh3 = (const float*)d_in[11];
  const float* b_ih3 = (const float*)d_in[12];
  const float* b_hh3 = (const float*)d_in[13];
  const float* w_dec = (const float*)d_in[14];
  const float* b_dec = (const float*)d_in[15];
  float* out = (float*)d_out;

  char* ws = (char*)d_ws;
  size_t off = 0;
  auto alloc = [&](size_t bytes) -> char* {
    off = (off + 255) & ~(size_t)255;
    char* p = ws + off;
    off += bytes;
    return p;
  };
  auto us = [&](size_t n) { return (unsigned short*)alloc(n * 2); };
  auto fl = [&](size_t n) { return (float*)alloc(n * 4); };

  const int NK1C = 48;  // cond L1: 6 x-chunks + 32 h-chunks = 38 real, pad to 48
  const int NK2 = 64;   // gen L1 / L2 / L3: 32 x + 32 h
  unsigned short* W1c = us((size_t)4096 * NK1C * 32);   // packed
  unsigned short* W1g = us((size_t)4096 * NK2 * 32);    // packed: ck0-31 Weff, 32-63 Whh1
  unsigned short* W2 = us((size_t)4096 * NK2 * 32);     // packed: Wih2 | Whh2
  unsigned short* W3 = us((size_t)4096 * NK2 * 32);     // packed: Wih3 | Whh3
  unsigned short* wd = us((size_t)OUTPAD * HID);
  unsigned short* wih1f = us((size_t)4096 * 192);
  unsigned short* wdt = us((size_t)1024 * 192);
  float *b1c = fl(4096), *beff = fl(4096), *b2 = fl(4096), *b3 = fl(4096), *bd = fl(OUTPAD);
  unsigned short *xch = us((size_t)TCOND * BATCH * INPAD), *xcl = us((size_t)TCOND * BATCH * INPAD);
  float* partials = fl((size_t)SPLITS * PSTR);
  unsigned short* histh = us((size_t)GENF * BATCH * HID);
  unsigned short* histl = us((size_t)GENF * BATCH * HID);

  size_t state_beg = (off + 255) & ~(size_t)255;
  float *c0 = fl((size_t)BATCH * HID), *c1 = fl((size_t)BATCH * HID), *c2 = fl((size_t)BATCH * HID);
  unsigned short* Hh[3][2];
  unsigned short* Hl[3][2];
  for (int L = 0; L < 3; ++L)
    for (int p = 0; p < 2; ++p) {
      Hh[L][p] = us((size_t)BATCH * HID);
      Hl[L][p] = us((size_t)BATCH * HID);
    }
  unsigned* counters = (unsigned*)alloc(TILES * 4);
  size_t state_end = off;

  if (off > ws_size) return;  // scratch too small; fail visibly

  hipMemsetAsync(ws + state_beg, 0, state_end - state_beg, stream);
  // zero W1c pad chunks (38..47)
  hipMemsetAsync(W1c, 0, (size_t)4096 * NK1C * 32 * 2, stream);

  // ---- weight / input prep ----
  cvt_w_pack_k<<<(4096 * INPAD + 255) / 256, 256, 0, stream>>>(w_ih1, W1c, INP, INPAD, 0, NK1C);
  cvt_w_pack_k<<<(4096 * 1024 + 255) / 256, 256, 0, stream>>>(w_hh1, W1c, HID, HID, 6, NK1C);
  cvt_w_pack_k<<<(4096 * 1024 + 255) / 256, 256, 0, stream>>>(w_hh1, W1g, HID, HID, 32, NK2);
  cvt_w_pack_k<<<(4096 * 1024 + 255) / 256, 256, 0, stream>>>(w_ih2, W2, HID, HID, 0, NK2);
  cvt_w_pack_k<<<(4096 * 1024 + 255) / 256, 256, 0, stream>>>(w_hh2, W2, HID, HID, 32, NK2);
  cvt_w_pack_k<<<(4096 * 1024 + 255) / 256, 256, 0, stream>>>(w_ih3, W3, HID, HID, 0, NK2);
  cvt_w_pack_k<<<(4096 * 1024 + 255) / 256, 256, 0, stream>>>(w_hh3, W3, HID, HID, 32, NK2);
  cvt_plain_k<<<(OUTPAD * HID + 255) / 256, 256, 0, stream>>>(w_dec, wd, OUTN, HID, OUTPAD, HID);
  cvt_plain_k<<<(4096 * 192 + 255) / 256, 256, 0, stream>>>(w_ih1, wih1f, 4096, INP, 4096, 192);
  cvt_wdt_k<<<(1024 * 192 + 255) / 256, 256, 0, stream>>>(w_dec, wdt);
  weff_k<<<4096, 256, 0, stream>>>(wih1f, wdt, W1g);
  beff_k<<<16, 256, 0, stream>>>(w_ih1, b_ih1, b_hh1, b_dec, beff);
  bias_perm_k<<<16, 256, 0, stream>>>(b_ih1, b_hh1, b1c);
  bias_perm_k<<<16, 256, 0, stream>>>(b_ih2, b_hh2, b2);
  bias_perm_k<<<16, 256, 0, stream>>>(b_ih3, b_hh3, b3);
  biaspad_k<<<1, 256, 0, stream>>>(b_dec, bd, OUTN, OUTPAD);
  xcond_k<<<(TCOND * BATCH * INPAD + 255) / 256, 256, 0, stream>>>(seq, xch, xcl);

  // ---- recurrent loop: 3 dispatches per step (decoder folded into gen-L1) ----
  for (int s = 0; s < TCOND + GENF; ++s) {
    const int pp = s & 1, np = pp ^ 1;
    unsigned short *hsh = (unsigned short*)0, *hsl = (unsigned short*)0;
    if (s >= TCOND) {
      hsh = histh + (size_t)(s - TCOND) * BATCH * HID;
      hsl = histl + (size_t)(s - TCOND) * BATCH * HID;
    }
    if (s < TCOND) {
      lstm_gemm_k<<<TILES * SPLITS, 256, 0, stream>>>(
          xch + (size_t)s * BATCH * INPAD, xcl + (size_t)s * BATCH * INPAD, INPAD, 6,
          Hh[0][pp], Hl[0][pp], W1c, NK1C, 38, b1c, c0,
          Hh[0][np], Hl[0][np], (unsigned short*)0, (unsigned short*)0,
          partials, counters);
    } else {
      lstm_gemm_k<<<TILES * SPLITS, 256, 0, stream>>>(
          Hh[2][pp], Hl[2][pp], HID, 32,
          Hh[0][pp], Hl[0][pp], W1g, NK2, NK2, beff, c0,
          Hh[0][np], Hl[0][np], (unsigned short*)0, (unsigned short*)0,
          partials, counters);
    }
    lstm_gemm_k<<<TILES * SPLITS, 256, 0, stream>>>(
        Hh[0][np], Hl[0][np], HID, 32,
        Hh[1][pp], Hl[1][pp], W2, NK2, NK2, b2, c1,
        Hh[1][np], Hl[1][np], (unsigned short*)0, (unsigned short*)0,
        partials, counters);
    lstm_gemm_k<<<TILES * SPLITS, 256, 0, stream>>>(
        Hh[1][np], Hl[1][np], HID, 32,
        Hh[2][pp], Hl[2][pp], W3, NK2, NK2, b3, c2,
        Hh[2][np], Hl[2][np], hsh, hsl,
        partials, counters);
  }

  // ---- batched decoder: all 100 outputs in one GEMM ----
  decb_k<<<(GENF * BATCH / 16) * 11, 256, 0, stream>>>(histh, histl, wd, bd, out);
}

// Round 19
// 12561.682 us; speedup vs baseline: 1.5040x; 1.1534x over previous
//
#include <hip/hip_runtime.h>

typedef __attribute__((ext_vector_type(8))) short short8;
typedef __attribute__((ext_vector_type(8))) _Float16 f16x8;
typedef __attribute__((ext_vector_type(4))) float f32x4;

#define GENF 100
#define TCOND 50
#define BATCH 128
#define HID 1024
#define INP 171
#define INPAD 192
#define OUTN 171
#define OUTPAD 176
#define SPLITS 4
#define TILES 64
#define PSTR ((size_t)BATCH * 4096)

static __device__ __forceinline__ unsigned short f2h(float f) {
  _Float16 h = (_Float16)f;
  return __builtin_bit_cast(unsigned short, h);
}
static __device__ __forceinline__ float h2f(unsigned short s) {
  return (float)__builtin_bit_cast(_Float16, s);
}
static __device__ __forceinline__ f16x8 ld8(const unsigned short* p) {
  short8 v = *reinterpret_cast<const short8*>(p);
  return __builtin_bit_cast(f16x8, v);
}
static __device__ __forceinline__ float sigm(float x) { return 1.f / (1.f + __expf(-x)); }

// Fused LSTM layer: fp16x2 split-K GEMM + PARALLEL finisher cell epilogue.
// W packed per (tile, chunk): Wp[nt][ck][64 cols][32 k] fp16 (R18).
// K-loop: R12-proven 3 rotating LDS bufs, depth-2 prefetch, counted vmcnt(20).
// Finisher (R19): counters are MONOTONIC (target passed per launch; workspace
// memset resets between replays). After RELEASE-arrival, ALL 4 split-blocks
// poll to target then each applies the cell to its own 32-row slice -> 4x
// parallel epilogue, 128KB reads/block, no reset store, no idle-block tail.
__global__ __launch_bounds__(256) void lstm_gemm_k(
    const unsigned short* __restrict__ xh_, const unsigned short* __restrict__ xl_,
    int ldx, int xc,
    const unsigned short* __restrict__ hh_, const unsigned short* __restrict__ hl_,
    const unsigned short* __restrict__ wP, int NKW, int nkr,
    const float* __restrict__ bias,
    float* __restrict__ c,
    unsigned short* __restrict__ ohh, unsigned short* __restrict__ ohl,
    unsigned short* __restrict__ histh, unsigned short* __restrict__ histl,
    float* __restrict__ partials, unsigned* __restrict__ counters, unsigned tgt)
{
  __shared__ __align__(16) char smem[98304];  // 3 bufs x 2 chunks x (hi 8K + lo 8K)
  const int t = threadIdx.x;
  const int lane = t & 63, wv = t >> 6;
  const int nt = blockIdx.x & (TILES - 1), sp = blockIdx.x >> 6;
  const int n0 = nt * 64 + wv * 16;
  const int nit = NKW / SPLITS;  // even
  const int beg = sp * nit;
  const int ns = nit >> 1;

  const int r_row = lane & 15, kg = lane >> 4;
  const int rslot = kg ^ (r_row & 3);
  const int srow = t >> 2;
  // packed W: lane's base within a chunk; chunk stride = 2048 elements (4KB)
  const unsigned short* wlane = wP + ((size_t)nt * NKW) * 2048
                                + (wv * 16 + r_row) * 32 + kg * 8;

  auto stage1 = [&](char* dst, int ck) {
    if (ck >= nkr) ck = 0;  // A staging clamp only (W pad chunks are zeroed)
    const unsigned short *sh, *sl;
    int ld, k0;
    if (ck < xc) { sh = xh_; sl = xl_; ld = ldx; k0 = ck * 32; }
    else { sh = hh_; sl = hl_; ld = HID; k0 = (ck - xc) * 32; }
#pragma unroll
    for (int j = 0; j < 2; ++j) {
      int rowp = j * 64 + srow;
      int slot = (t & 3) ^ (rowp & 3);
      const unsigned short* gh = sh + (size_t)rowp * ld + k0 + slot * 8;
      const unsigned short* gl = sl + (size_t)rowp * ld + k0 + slot * 8;
      char* dh = dst + j * 4096 + wv * 1024;
      char* dl = dst + 8192 + j * 4096 + wv * 1024;
      __builtin_amdgcn_global_load_lds((const __attribute__((address_space(1))) void*)gh,
                                       (__attribute__((address_space(3))) void*)dh, 16, 0, 0);
      __builtin_amdgcn_global_load_lds((const __attribute__((address_space(1))) void*)gl,
                                       (__attribute__((address_space(3))) void*)dl, 16, 0, 0);
    }
  };

  f32x4 zz = {0.f, 0.f, 0.f, 0.f};
  f32x4 acc[8] = {zz, zz, zz, zz, zz, zz, zz, zz};

  char* bA = smem;
  char* bB = smem + 32768;
  char* bC = smem + 65536;

  stage1(bA, beg);
  stage1(bA + 16384, beg + 1);
  f16x8 b0h0 = ld8(wlane + (size_t)(beg + 0) * 2048);
  f16x8 b0h1 = ld8(wlane + (size_t)(beg + 1) * 2048);
  __builtin_amdgcn_sched_barrier(0);
  stage1(bB, beg + 2);
  stage1(bB + 16384, beg + 3);
  f16x8 b1h0 = ld8(wlane + (size_t)(beg + 2) * 2048);
  f16x8 b1h1 = ld8(wlane + (size_t)(beg + 3) * 2048);
  __builtin_amdgcn_sched_barrier(0);

  for (int i = 0; i < ns; ++i) {
    int ck = beg + 2 * i + 4;
    if (ck >= beg + nit) ck = beg;  // junk tail (uniform counts, unused)
    stage1(bC, ck);
    stage1(bC + 16384, ck + 1);
    f16x8 b2h0 = ld8(wlane + (size_t)ck * 2048);
    f16x8 b2h1 = ld8(wlane + (size_t)(ck + 1) * 2048);
    __builtin_amdgcn_sched_barrier(0);

    asm volatile("s_waitcnt vmcnt(20)" ::: "memory");
    __builtin_amdgcn_s_barrier();
    __builtin_amdgcn_sched_barrier(0);

#pragma unroll
    for (int ch = 0; ch < 2; ++ch) {
      f16x8 ah[8], al[8];
#pragma unroll
      for (int rg = 0; rg < 8; ++rg) {
        int ro = ch * 16384 + (rg * 16 + r_row) * 64 + rslot * 16;
        ah[rg] = *reinterpret_cast<const f16x8*>(bA + ro);
        al[rg] = *reinterpret_cast<const f16x8*>(bA + ro + 8192);
      }
      f16x8 BH = ch ? b0h1 : b0h0;
#pragma unroll
      for (int rg = 0; rg < 8; ++rg)
        acc[rg] = __builtin_amdgcn_mfma_f32_16x16x32_f16(ah[rg], BH, acc[rg], 0, 0, 0);
#pragma unroll
      for (int rg = 0; rg < 8; ++rg)
        acc[rg] = __builtin_amdgcn_mfma_f32_16x16x32_f16(al[rg], BH, acc[rg], 0, 0, 0);
    }
    __builtin_amdgcn_sched_barrier(0);
    __builtin_amdgcn_s_barrier();

    char* tmp = bA; bA = bB; bB = bC; bC = tmp;
    b0h0 = b1h0; b0h1 = b1h1;
    b1h0 = b2h0; b1h1 = b2h1;
  }

  // ---- store split partials ----
  {
    float* pb = partials + (size_t)sp * PSTR;
    const int cn = n0 + r_row;
    const int mb = kg * 4;
#pragma unroll
    for (int rg = 0; rg < 8; ++rg)
#pragma unroll
      for (int r = 0; r < 4; ++r)
        pb[(size_t)(rg * 16 + mb + r) * 4096 + cn] = acc[rg][r];
  }

  __syncthreads();  // drain stores + junk staging
  if (t == 0)
    __hip_atomic_fetch_add(&counters[nt], 1u, __ATOMIC_RELEASE, __HIP_MEMORY_SCOPE_AGENT);
  // all blocks wait until all SPLITS arrivals for this tile (monotonic target)
  if (t == 0) {
    while (__hip_atomic_load(&counters[nt], __ATOMIC_RELAXED, __HIP_MEMORY_SCOPE_AGENT) < tgt)
      __builtin_amdgcn_s_sleep(2);
    (void)__hip_atomic_load(&counters[nt], __ATOMIC_ACQUIRE, __HIP_MEMORY_SCOPE_AGENT);
  }
  __syncthreads();

  // ---- parallel finisher: this block handles rows [sp*32, sp*32+32) ----
  const int fc = t & 15, fm = t >> 4;
  const int nh = nt * 16 + fc;
  const f32x4 bv = *reinterpret_cast<const f32x4*>(&bias[nh * 4]);
#pragma unroll
  for (int p = 0; p < 2; ++p) {
    int m = sp * 32 + p * 16 + fm;
    size_t gi0 = (size_t)m * 4096 + nh * 4;
    f32x4 s = *reinterpret_cast<const f32x4*>(&partials[gi0]);
#pragma unroll
    for (int q = 1; q < SPLITS; ++q)
      s += *reinterpret_cast<const f32x4*>(&partials[gi0 + (size_t)q * PSTR]);
    float gi = sigm(s[0] + bv[0]);
    float gf = sigm(s[1] + bv[1]);
    float gg = tanhf(s[2] + bv[2]);
    float go = sigm(s[3] + bv[3]);
    size_t sidx = (size_t)m * HID + nh;
    float cn2 = gf * c[sidx] + gi * gg;
    c[sidx] = cn2;
    float h = go * tanhf(cn2);
    unsigned short h16 = f2h(h);
    unsigned short l16 = f2h(h - h2f(h16));
    ohh[sidx] = h16;
    ohl[sidx] = l16;
    if (histh) { histh[sidx] = h16; histl[sidx] = l16; }
  }
}

// Batched decoder over history: out[b][t][:] = hist[t*128+b] @ wd^T + bd.
__global__ __launch_bounds__(256) void decb_k(
    const unsigned short* __restrict__ histh, const unsigned short* __restrict__ histl,
    const unsigned short* __restrict__ wdh, const float* __restrict__ bd,
    float* __restrict__ outp)
{
  const int wave = threadIdx.x >> 6, lane = threadIdx.x & 63;
  const int n0 = ((int)blockIdx.x % 11) * 16;
  const int m0 = ((int)blockIdx.x / 11) * 16;
  const int row = lane & 15, kg = lane >> 4;
  f32x4 acc = {0.f, 0.f, 0.f, 0.f};
  const unsigned short* pah = histh + (size_t)(m0 + row) * HID + kg * 8 + wave * 256;
  const unsigned short* pal = histl + (size_t)(m0 + row) * HID + kg * 8 + wave * 256;
  const unsigned short* pbh = wdh + (size_t)(n0 + row) * HID + kg * 8 + wave * 256;
#pragma unroll
  for (int kk = 0; kk < 8; ++kk) {
    int off = kk * 32;
    f16x8 a1 = ld8(pah + off), a2 = ld8(pal + off);
    f16x8 b1 = ld8(pbh + off);
    acc = __builtin_amdgcn_mfma_f32_16x16x32_f16(a1, b1, acc, 0, 0, 0);
    acc = __builtin_amdgcn_mfma_f32_16x16x32_f16(a2, b1, acc, 0, 0, 0);
  }
  __shared__ f32x4 red[4][64];
  if (wave) red[wave][lane] = acc;
  __syncthreads();
  if (wave == 0) {
    acc += red[1][lane];
    acc += red[2][lane];
    acc += red[3][lane];
    const int col = lane & 15, rg = lane >> 4;
#pragma unroll
    for (int r = 0; r < 4; ++r) {
      int m = m0 + rg * 4 + r;
      int n = n0 + col;
      if (n < OUTN) {
        int tt = m >> 7, b = m & 127;
        outp[(size_t)b * (GENF * OUTN) + (size_t)tt * OUTN + n] = acc[r] + bd[n];
      }
    }
  }
}

// ---- prep kernels ----
// LSTM weight -> PACKED: src [4096 gate-major rows][C] f32; perm row rp=(r&1023)*4+(r>>10);
// dst[((nt*NKW + ck0 + cc/32)*64 + (rp&63))*32 + cc%32] fp16, nt = rp>>6.
__global__ void cvt_w_pack_k(const float* __restrict__ src, unsigned short* __restrict__ dst,
                             int C, int Cpad, int ck0, int NKW)
{
  int idx = blockIdx.x * 256 + threadIdx.x;
  if (idx >= 4096 * Cpad) return;
  int r = idx / Cpad, cc = idx - r * Cpad;
  float v = (cc < C) ? src[(size_t)r * C + cc] : 0.f;
  int rp = (r & 1023) * 4 + (r >> 10);
  int nt = rp >> 6, nc = rp & 63;
  int ck = ck0 + (cc >> 5), kk = cc & 31;
  dst[(((size_t)nt * NKW + ck) * 64 + nc) * 32 + kk] = f2h(v);
}

// plain fp16 cvt with row/col pad (no perm)
__global__ void cvt_plain_k(const float* __restrict__ src, unsigned short* __restrict__ w16,
                            int R, int C, int Rp, int Cp)
{
  int idx = blockIdx.x * 256 + threadIdx.x;
  if (idx >= Rp * Cp) return;
  int r = idx / Cp, c2 = idx - r * Cp;
  float v = (r < R && c2 < C) ? src[(size_t)r * C + c2] : 0.f;
  w16[idx] = f2h(v);
}

// transposed dec weight: wdt[k][j] = w_dec[j][k], [1024][192] fp16 (pad j>=171 -> 0)
__global__ void cvt_wdt_k(const float* __restrict__ wdec, unsigned short* __restrict__ wdt)
{
  int idx = blockIdx.x * 256 + threadIdx.x;
  if (idx >= 1024 * 192) return;
  int k = idx / 192, j = idx - k * 192;
  float v = (j < OUTN) ? wdec[(size_t)j * HID + k] : 0.f;
  wdt[idx] = f2h(v);
}

// Weff = Wih1 @ Wd : [4096 perm rows][1024], written PACKED into W1g chunks 0..31.
__global__ __launch_bounds__(256) void weff_k(
    const unsigned short* __restrict__ wih, const unsigned short* __restrict__ wdt,
    unsigned short* __restrict__ W1g)
{
  const int wave = threadIdx.x >> 6, lane = threadIdx.x & 63;
  const int tile = blockIdx.x * 4 + wave;
  const int m0 = (tile >> 6) * 16;   // i
  const int n0 = (tile & 63) * 16;   // k2
  const int row = lane & 15, kg = lane >> 4;
  f32x4 acc = {0.f, 0.f, 0.f, 0.f};
  const unsigned short* pa = wih + (size_t)(m0 + row) * 192 + kg * 8;
  const unsigned short* pb = wdt + (size_t)(n0 + row) * 192 + kg * 8;
#pragma unroll
  for (int kk = 0; kk < 6; ++kk) {
    int off = kk * 32;
    f16x8 a = ld8(pa + off);
    f16x8 b = ld8(pb + off);
    acc = __builtin_amdgcn_mfma_f32_16x16x32_f16(a, b, acc, 0, 0, 0);
  }
  const int col = lane & 15, rg = lane >> 4;
#pragma unroll
  for (int r = 0; r < 4; ++r) {
    int i = m0 + rg * 4 + r;
    int k2 = n0 + col;
    int rp = (i & 1023) * 4 + (i >> 10);
    int nt = rp >> 6, nc = rp & 63;
    int ck = k2 >> 5, kk2 = k2 & 31;
    W1g[(((size_t)nt * 64 + ck) * 64 + nc) * 32 + kk2] = f2h(acc[r]);
  }
}

// beff[rp(i)] = b_ih1[i] + b_hh1[i] + sum_j Wih1[i][j] * b_dec[j]  (fp32)
__global__ void beff_k(const float* __restrict__ wih1, const float* __restrict__ bih,
                       const float* __restrict__ bhh, const float* __restrict__ bdec,
                       float* __restrict__ dst)
{
  int i = blockIdx.x * 256 + threadIdx.x;
  if (i >= 4096) return;
  float a = bih[i] + bhh[i];
  for (int j = 0; j < OUTN; ++j) a += wih1[(size_t)i * OUTN + j] * bdec[j];
  dst[(i & 1023) * 4 + (i >> 10)] = a;
}

__global__ void bias_perm_k(const float* __restrict__ a, const float* __restrict__ b,
                            float* __restrict__ dst)
{
  int i = blockIdx.x * 256 + threadIdx.x;
  if (i < 4096) dst[(i & 1023) * 4 + (i >> 10)] = a[i] + b[i];
}

__global__ void biaspad_k(const float* __restrict__ a, float* __restrict__ dst, int n, int np)
{
  int i = blockIdx.x * 256 + threadIdx.x;
  if (i < np) dst[i] = (i < n) ? a[i] : 0.f;
}

// initial_seq [B][T][IN] fp32 -> xcond hi/lo [T][B][INPAD] fp16
__global__ void xcond_k(const float* __restrict__ seq, unsigned short* __restrict__ xhi,
                        unsigned short* __restrict__ xlo)
{
  int idx = blockIdx.x * 256 + threadIdx.x;
  const int total = TCOND * BATCH * INPAD;
  if (idx >= total) return;
  int t = idx / (BATCH * INPAD);
  int rem = idx - t * (BATCH * INPAD);
  int b = rem / INPAD;
  int k = rem - b * INPAD;
  float v = (k < INP) ? seq[((size_t)b * TCOND + t) * INP + k] : 0.f;
  unsigned short h = f2h(v);
  xhi[idx] = h;
  xlo[idx] = f2h(v - h2f(h));
}

extern "C" void kernel_launch(void* const* d_in, const int* in_sizes, int n_in,
                              void* d_out, int out_size, void* d_ws, size_t ws_size,
                              hipStream_t stream)
{
  (void)in_sizes; (void)n_in; (void)out_size;
  const float* seq   = (const float*)d_in[0];
  const float* w_ih1 = (const float*)d_in[2];
  const float* w_hh1 = (const float*)d_in[3];
  const float* b_ih1 = (const float*)d_in[4];
  const float* b_hh1 = (const float*)d_in[5];
  const float* w_ih2 = (const float*)d_in[6];
  const float* w_hh2 = (const float*)d_in[7];
  const float* b_ih2 = (const float*)d_in[8];
  const float* b_hh2 = (const float*)d_in[9];
  const float* w_ih3 = (const float*)d_in[10];
  const float* w_hh3 = (const float*)d_in[11];
  const float* b_ih3 = (const float*)d_in[12];
  const float* b_hh3 = (const float*)d_in[13];
  const float* w_dec = (const float*)d_in[14];
  const float* b_dec = (const float*)d_in[15];
  float* out = (float*)d_out;

  char* ws = (char*)d_ws;
  size_t off = 0;
  auto alloc = [&](size_t bytes) -> char* {
    off = (off + 255) & ~(size_t)255;
    char* p = ws + off;
    off += bytes;
    return p;
  };
  auto us = [&](size_t n) { return (unsigned short*)alloc(n * 2); };
  auto fl = [&](size_t n) { return (float*)alloc(n * 4); };

  const int NK1C = 48;  // cond L1: 6 x-chunks + 32 h-chunks = 38 real, pad to 48
  const int NK2 = 64;   // gen L1 / L2 / L3: 32 x + 32 h
  unsigned short* W1c = us((size_t)4096 * NK1C * 32);   // packed
  unsigned short* W1g = us((size_t)4096 * NK2 * 32);    // packed: ck0-31 Weff, 32-63 Whh1
  unsigned short* W2 = us((size_t)4096 * NK2 * 32);     // packed: Wih2 | Whh2
  unsigned short* W3 = us((size_t)4096 * NK2 * 32);     // packed: Wih3 | Whh3
  unsigned short* wd = us((size_t)OUTPAD * HID);
  unsigned short* wih1f = us((size_t)4096 * 192);
  unsigned short* wdt = us((size_t)1024 * 192);
  float *b1c = fl(4096), *beff = fl(4096), *b2 = fl(4096), *b3 = fl(4096), *bd = fl(OUTPAD);
  unsigned short *xch = us((size_t)TCOND * BATCH * INPAD), *xcl = us((size_t)TCOND * BATCH * INPAD);
  float* partials = fl((size_t)SPLITS * PSTR);
  unsigned short* histh = us((size_t)GENF * BATCH * HID);
  unsigned short* histl = us((size_t)GENF * BATCH * HID);

  size_t state_beg = (off + 255) & ~(size_t)255;
  float *c0 = fl((size_t)BATCH * HID), *c1 = fl((size_t)BATCH * HID), *c2 = fl((size_t)BATCH * HID);
  unsigned short* Hh[3][2];
  unsigned short* Hl[3][2];
  for (int L = 0; L < 3; ++L)
    for (int p = 0; p < 2; ++p) {
      Hh[L][p] = us((size_t)BATCH * HID);
      Hl[L][p] = us((size_t)BATCH * HID);
    }
  unsigned* counters = (unsigned*)alloc(3 * TILES * 4);  // monotonic, zeroed each call
  size_t state_end = off;

  if (off > ws_size) return;  // scratch too small; fail visibly

  hipMemsetAsync(ws + state_beg, 0, state_end - state_beg, stream);
  // zero W1c pad chunks (38..47)
  hipMemsetAsync(W1c, 0, (size_t)4096 * NK1C * 32 * 2, stream);

  // ---- weight / input prep ----
  cvt_w_pack_k<<<(4096 * INPAD + 255) / 256, 256, 0, stream>>>(w_ih1, W1c, INP, INPAD, 0, NK1C);
  cvt_w_pack_k<<<(4096 * 1024 + 255) / 256, 256, 0, stream>>>(w_hh1, W1c, HID, HID, 6, NK1C);
  cvt_w_pack_k<<<(4096 * 1024 + 255) / 256, 256, 0, stream>>>(w_hh1, W1g, HID, HID, 32, NK2);
  cvt_w_pack_k<<<(4096 * 1024 + 255) / 256, 256, 0, stream>>>(w_ih2, W2, HID, HID, 0, NK2);
  cvt_w_pack_k<<<(4096 * 1024 + 255) / 256, 256, 0, stream>>>(w_hh2, W2, HID, HID, 32, NK2);
  cvt_w_pack_k<<<(4096 * 1024 + 255) / 256, 256, 0, stream>>>(w_ih3, W3, HID, HID, 0, NK2);
  cvt_w_pack_k<<<(4096 * 1024 + 255) / 256, 256, 0, stream>>>(w_hh3, W3, HID, HID, 32, NK2);
  cvt_plain_k<<<(OUTPAD * HID + 255) / 256, 256, 0, stream>>>(w_dec, wd, OUTN, HID, OUTPAD, HID);
  cvt_plain_k<<<(4096 * 192 + 255) / 256, 256, 0, stream>>>(w_ih1, wih1f, 4096, INP, 4096, 192);
  cvt_wdt_k<<<(1024 * 192 + 255) / 256, 256, 0, stream>>>(w_dec, wdt);
  weff_k<<<4096, 256, 0, stream>>>(wih1f, wdt, W1g);
  beff_k<<<16, 256, 0, stream>>>(w_ih1, b_ih1, b_hh1, b_dec, beff);
  bias_perm_k<<<16, 256, 0, stream>>>(b_ih1, b_hh1, b1c);
  bias_perm_k<<<16, 256, 0, stream>>>(b_ih2, b_hh2, b2);
  bias_perm_k<<<16, 256, 0, stream>>>(b_ih3, b_hh3, b3);
  biaspad_k<<<1, 256, 0, stream>>>(b_dec, bd, OUTN, OUTPAD);
  xcond_k<<<(TCOND * BATCH * INPAD + 255) / 256, 256, 0, stream>>>(seq, xch, xcl);

  // ---- recurrent loop: 3 dispatches per step (decoder folded into gen-L1) ----
  for (int s = 0; s < TCOND + GENF; ++s) {
    const int pp = s & 1, np = pp ^ 1;
    const unsigned tg = (unsigned)SPLITS * (unsigned)(s + 1);
    unsigned short *hsh = (unsigned short*)0, *hsl = (unsigned short*)0;
    if (s >= TCOND) {
      hsh = histh + (size_t)(s - TCOND) * BATCH * HID;
      hsl = histl + (size_t)(s - TCOND) * BATCH * HID;
    }
    if (s < TCOND) {
      lstm_gemm_k<<<TILES * SPLITS, 256, 0, stream>>>(
          xch + (size_t)s * BATCH * INPAD, xcl + (size_t)s * BATCH * INPAD, INPAD, 6,
          Hh[0][pp], Hl[0][pp], W1c, NK1C, 38, b1c, c0,
          Hh[0][np], Hl[0][np], (unsigned short*)0, (unsigned short*)0,
          partials, counters, tg);
    } else {
      lstm_gemm_k<<<TILES * SPLITS, 256, 0, stream>>>(
          Hh[2][pp], Hl[2][pp], HID, 32,
          Hh[0][pp], Hl[0][pp], W1g, NK2, NK2, beff, c0,
          Hh[0][np], Hl[0][np], (unsigned short*)0, (unsigned short*)0,
          partials, counters, tg);
    }
    lstm_gemm_k<<<TILES * SPLITS, 256, 0, stream>>>(
        Hh[0][np], Hl[0][np], HID, 32,
        Hh[1][pp], Hl[1][pp], W2, NK2, NK2, b2, c1,
        Hh[1][np], Hl[1][np], (unsigned short*)0, (unsigned short*)0,
        partials, counters + TILES, tg);
    lstm_gemm_k<<<TILES * SPLITS, 256, 0, stream>>>(
        Hh[1][np], Hl[1][np], HID, 32,
        Hh[2][pp], Hl[2][pp], W3, NK2, NK2, b3, c2,
        Hh[2][np], Hl[2][np], hsh, hsl,
        partials, counters + 2 * TILES, tg);
  }

  // ---- batched decoder: all 100 outputs in one GEMM ----
  decb_k<<<(GENF * BATCH / 16) * 11, 256, 0, stream>>>(histh, histl, wd, bd, out);
}